// Round 6
// baseline (169.357 us; speedup 1.0000x reference)
//
#include <hip/hip_runtime.h>

#define N_NODES 100000
#define N_EDGES 1600000
#define IN_F 128
#define OUT_F 64

#define BROWS 32               // rows per bucket (100000 = 32 * 3125)
#define NBUCKET 3125
#define CAP 1024               // max edges a gather block sorts (mean 512, std 22.6)
#define BK_PAD 136             // padded k-stride (shorts) for b_lds: breaks 16-way bank repeat

#define NCHUNK 256             // edge chunks; == gather blockDim so thread==chunk
#define EPC (N_EDGES / NCHUNK) // 6250 edges per chunk (exact)
#define NPOS (NBUCKET + 1)     // 3126: per-chunk prefix incl. sentinel
#define GEMM_BLKS ((N_NODES + 127) / 128)   // 782: gemm sub-blocks (128 rows each)

typedef __attribute__((ext_vector_type(8))) short bf16x8;
typedef __attribute__((ext_vector_type(4))) float f32x4;

__device__ __forceinline__ unsigned short f32_to_bf16(float f) {
    const unsigned int b = __float_as_uint(f);
    return (unsigned short)((b + 0x7FFFu + ((b >> 16) & 1u)) >> 16);   // RNE
}
__device__ __forceinline__ float bf16_to_f32(unsigned short u) {
    return __uint_as_float(((unsigned int)u) << 16);
}
// unpack low/high bf16 of a uint32 (1 VALU each)
__device__ __forceinline__ float bflo(unsigned int u) { return __uint_as_float(u << 16); }
__device__ __forceinline__ float bfhi(unsigned int u) { return __uint_as_float(u & 0xFFFF0000u); }

// ---------------- Kernel 1: FUSED  gemm (blocks >= NCHUNK) + chunk-sort (blocks < NCHUNK) ----
// Union LDS is now max(12.5, 17.4) = 17.4 KB (r5's 62.6 KB union capped ALL blocks at
// 2/CU and cost the gemm branch ~3x occupancy). The sort branch scatters DIRECTLY to
// its 50 KB chunk window in sedge: ~32 concurrent windows/XCD = 1.6 MB << 4 MB L2, so
// each 64B line absorbs its 8 scattered 8B stores and evicts once (windowed scatter,
// unlike r0's device-wide scatter that hit 7x write amp).
//
// gemm: 512 thr = 8 waves; wave = 16 rows x 64 cols via MFMA 16x16x32 bf16. W transposed
// in LDS as [n][k] bf16 (pad 136) -> b-frags are ds_read_b128. Frag layouts
// (m89/m91-verified): A: m=lane&15,k=quad*8+j. B: n=lane&15,k=quad*8+j.
// C/D: col=lane&15, row=quad*4+r.
__global__ __launch_bounds__(512) void gemm_sort_kernel(
    const float* __restrict__ x, const float* __restrict__ w,
    unsigned short* __restrict__ support,
    const int* __restrict__ erow, const int* __restrict__ ecol,
    const float* __restrict__ evals, int* __restrict__ pos_g,
    uint2* __restrict__ sedge) {
    __shared__ union {
        struct { int pos[NPOS]; int wofs[8]; } s;   // 12.5 KB (sort)
        unsigned short b[OUT_F * BK_PAD];           // 17.4 KB (gemm)
    } u;

    const int t = threadIdx.x;

    if (blockIdx.x < NCHUNK) {
        // ================= sort branch =================
        int* pos = u.s.pos;
        const int c = blockIdx.x;
        const size_t e0 = (size_t)c * EPC;

        for (int i = t; i < NPOS; i += 512) pos[i] = 0;
        __syncthreads();

        // pass 1: histogram (erow re-read in pass 2 is L2-hot: 25 KB slice/block)
        #pragma unroll 1
        for (int j = t; j < EPC; j += 512)
            atomicAdd(&pos[erow[e0 + j] >> 5], 1);
        __syncthreads();

        // block-exclusive scan over 3125 buckets, 7 per thread (512*7 = 3584 >= 3126)
        int v[7]; int s = 0;
        #pragma unroll
        for (int j = 0; j < 7; ++j) {
            const int i = t * 7 + j;
            v[j] = (i < NBUCKET) ? pos[i] : 0;
            s += v[j];
        }
        const int lane = t & 63, wid = t >> 6;
        int incl = s;
        #pragma unroll
        for (int d = 1; d < 64; d <<= 1) { int tv = __shfl_up(incl, d); if (lane >= d) incl += tv; }
        if (lane == 63) u.s.wofs[wid] = incl;
        __syncthreads();
        int wbase = 0;
        #pragma unroll
        for (int wj = 0; wj < 8; ++wj) wbase += (wj < wid) ? u.s.wofs[wj] : 0;
        int ex = wbase + incl - s;
        #pragma unroll
        for (int j = 0; j < 7; ++j) {
            const int i = t * 7 + j;
            if (i < NBUCKET) { pos[i] = ex; ex += v[j]; }   // own indices only: no hazard
        }
        if (t == 0) pos[NBUCKET] = EPC;
        __syncthreads();

        // persist per-chunk prefix (coalesced); gather reads it directly (L2-resident)
        int* pg = pos_g + (size_t)c * NPOS;
        for (int i = t; i < NPOS; i += 512) pg[i] = pos[i];
        __syncthreads();   // persist reads must finish before cursors mutate

        // pass 2: rank + DIRECT windowed scatter to sedge[e0 .. e0+EPC)
        #pragma unroll 1
        for (int j = t; j < EPC; j += 512) {
            const int row = erow[e0 + j];
            const int col = ecol[e0 + j];
            const float val = evals[e0 + j];
            const int r = atomicAdd(&pos[row >> 5], 1);
            uint2 ed;
            ed.x = (unsigned int)col | (((unsigned int)row & 31u) << 20);
            ed.y = __float_as_uint(val);
            sedge[e0 + r] = ed;
        }
        return;
    }

    // ================= gemm branch =================
    const int bb = blockIdx.x - NCHUNK;
    // stage W transposed: w[k][n] (fp32, coalesced float4) -> b[n*BK_PAD + k] (bf16)
    #pragma unroll
    for (int i = 0; i < 4; ++i) {
        const int f = t + 512 * i;            // float4 index; k = f>>4, n4 = (f&15)*4
        const int k = f >> 4, n4 = (f & 15) * 4;
        const float4 wv = ((const float4*)w)[f];
        u.b[(n4 + 0) * BK_PAD + k] = f32_to_bf16(wv.x);
        u.b[(n4 + 1) * BK_PAD + k] = f32_to_bf16(wv.y);
        u.b[(n4 + 2) * BK_PAD + k] = f32_to_bf16(wv.z);
        u.b[(n4 + 3) * BK_PAD + k] = f32_to_bf16(wv.w);
    }
    __syncthreads();

    const int lane = t & 63, wid = t >> 6;
    const int m16 = lane & 15, quad = lane >> 4;
    const int row0 = bb * 128 + wid * 16;
    const int arow = min(row0 + m16, N_NODES - 1);
    const float* xr = x + (size_t)arow * IN_F;

    f32x4 acc[4];
    #pragma unroll
    for (int nt = 0; nt < 4; ++nt) acc[nt] = (f32x4){0.f, 0.f, 0.f, 0.f};

    #pragma unroll
    for (int kt = 0; kt < 4; ++kt) {
        const int kb = kt * 32 + quad * 8;
        const float4 a0 = *(const float4*)(xr + kb);
        const float4 a1 = *(const float4*)(xr + kb + 4);
        bf16x8 af;
        af[0] = (short)f32_to_bf16(a0.x); af[1] = (short)f32_to_bf16(a0.y);
        af[2] = (short)f32_to_bf16(a0.z); af[3] = (short)f32_to_bf16(a0.w);
        af[4] = (short)f32_to_bf16(a1.x); af[5] = (short)f32_to_bf16(a1.y);
        af[6] = (short)f32_to_bf16(a1.z); af[7] = (short)f32_to_bf16(a1.w);
        #pragma unroll
        for (int nt = 0; nt < 4; ++nt) {
            const bf16x8 bf = *(const bf16x8*)&u.b[(nt * 16 + m16) * BK_PAD + kb];
            acc[nt] = __builtin_amdgcn_mfma_f32_16x16x32_bf16(af, bf, acc[nt], 0, 0, 0);
        }
    }

    #pragma unroll
    for (int nt = 0; nt < 4; ++nt) {
        #pragma unroll
        for (int r = 0; r < 4; ++r) {
            const int row = row0 + quad * 4 + r;
            if (row < N_NODES)
                support[(size_t)row * OUT_F + nt * 16 + m16] = f32_to_bf16(acc[nt][r]);
        }
    }
}

// ---------------- Kernel 2: gather = run-fetch + counting-sort by row + accumulation ---------
// EXACT r3 structure (proven 44.4us: single-pass run front-end, single-row 4-group
// back-end) with one change: run bounds read directly from pos_g[t][k..k+1] (same
// cache line; pos_g 3.2 MB -> L2-resident/XCD) instead of a transposed posT — kills
// the transpose kernel + its ~10us launch. Bijective XCD swizzle (m204) keeps
// adjacent buckets (shared sedge/pos_g lines) on the same XCD L2.
__global__ __launch_bounds__(256) void gather_kernel(
    const unsigned short* __restrict__ support, const uint2* __restrict__ sedge,
    const int* __restrict__ pos_g, const float* __restrict__ bias,
    float* __restrict__ out) {
    __shared__ uint2 tmp[CAP];      // 8 KB arrival-order edges
    __shared__ uint2 sdata[CAP];    // 8 KB row-sorted edges
    __shared__ int bcnt[BROWS];
    __shared__ int bptr[BROWS + 1];
    __shared__ int boff[BROWS];
    __shared__ int wsum[4];

    const int t = threadIdx.x;
    // nwg = 3125 = 8*390 + 5: xcd<5 owns 391 buckets, else 390 (bijective, m204)
    const int orig = blockIdx.x;
    const int xcd = orig & 7, loc = orig >> 3;
    const int k = (xcd < 5 ? xcd * 391 : 5 * 391 + (xcd - 5) * 390) + loc;
    const int lane = t & 63, wid = t >> 6;

    // run descriptor for chunk t: pos_g[t][k], pos_g[t][k+1] share one 64B line
    const int s = pos_g[(size_t)t * NPOS + k];
    const int e = pos_g[(size_t)t * NPOS + k + 1];
    const int L = e - s;

    // block scan of run lengths -> arrival offset
    int incl = L;
    #pragma unroll
    for (int d = 1; d < 64; d <<= 1) { int tv = __shfl_up(incl, d); if (lane >= d) incl += tv; }
    if (lane == 63) wsum[wid] = incl;
    if (t < BROWS) bcnt[t] = 0;
    __syncthreads();
    int wbase = 0;
    #pragma unroll
    for (int wj = 0; wj < 4; ++wj) wbase += (wj < wid) ? wsum[wj] : 0;
    const int ofs = wbase + incl - L;
    const int ntot = wsum[0] + wsum[1] + wsum[2] + wsum[3];
    const int n = min(ntot, CAP);

    // stash runs into tmp (arrival order); avg L = 2
    const uint2* myrun = sedge + (size_t)t * EPC + s;
    for (int j = 0; j < L; ++j) {
        const int p = ofs + j;
        if (p < CAP) tmp[p] = myrun[j];
    }
    __syncthreads();

    // counting sort by row-in-bucket
    uint2 my[4]; int mb[4];
    #pragma unroll
    for (int j = 0; j < 4; ++j) {
        const int i = t + j * 256;
        mb[j] = -1;
        if (i < n) {
            my[j] = tmp[i];
            mb[j] = (my[j].x >> 20) & 31;
            atomicAdd(&bcnt[mb[j]], 1);
        }
    }
    __syncthreads();

    if (t < 64) {
        const int v = (t < BROWS) ? bcnt[t] : 0;
        int incl2 = v;
        #pragma unroll
        for (int d = 1; d < 32; d <<= 1) { int tv = __shfl_up(incl2, d); if (t >= d) incl2 += tv; }
        if (t < BROWS) { bptr[t] = incl2 - v; boff[t] = incl2 - v; }
        if (t == BROWS - 1) bptr[BROWS] = incl2;
    }
    __syncthreads();

    #pragma unroll
    for (int j = 0; j < 4; ++j) {
        if (mb[j] >= 0) {
            const int p = atomicAdd(&boff[mb[j]], 1);
            sdata[p] = my[j];
        }
    }
    __syncthreads();

    const int eg = lane >> 4;          // edge-group 0..3
    const int c4 = lane & 15;          // col-quad: cols 4*c4 .. 4*c4+3
    const float4 bb = ((const float4*)bias)[c4];

    for (int r8 = 0; r8 < 8; ++r8) {
        const int r = wid * 8 + r8;
        const int s0 = bptr[r], s1 = bptr[r + 1];
        float a0 = 0.f, a1 = 0.f, a2 = 0.f, a3 = 0.f;
        int j = s0;
        for (; j + 8 <= s1; j += 8) {            // 2 quads in flight
            const uint2 e0 = sdata[j + eg];
            const uint2 e1 = sdata[j + 4 + eg];
            const uint2 g0 = *(const uint2*)(support + (size_t)(e0.x & 0xFFFFFu) * OUT_F + c4 * 4);
            const uint2 g1 = *(const uint2*)(support + (size_t)(e1.x & 0xFFFFFu) * OUT_F + c4 * 4);
            const float v0 = __uint_as_float(e0.y), v1 = __uint_as_float(e1.y);
            a0 += v0 * bflo(g0.x); a1 += v0 * bfhi(g0.x);
            a2 += v0 * bflo(g0.y); a3 += v0 * bfhi(g0.y);
            a0 += v1 * bflo(g1.x); a1 += v1 * bfhi(g1.x);
            a2 += v1 * bflo(g1.y); a3 += v1 * bfhi(g1.y);
        }
        for (; j < s1; j += 4) {                 // predicated quad tail
            const int jj = j + eg;
            const bool act = jj < s1;
            const uint2 ed = sdata[act ? jj : j];
            const float v = act ? __uint_as_float(ed.y) : 0.f;
            const uint2 gv = *(const uint2*)(support + (size_t)(ed.x & 0xFFFFFu) * OUT_F + c4 * 4);
            a0 += v * bflo(gv.x); a1 += v * bfhi(gv.x);
            a2 += v * bflo(gv.y); a3 += v * bfhi(gv.y);
        }
        a0 += __shfl_xor(a0, 16); a0 += __shfl_xor(a0, 32);
        a1 += __shfl_xor(a1, 16); a1 += __shfl_xor(a1, 32);
        a2 += __shfl_xor(a2, 16); a2 += __shfl_xor(a2, 32);
        a3 += __shfl_xor(a3, 16); a3 += __shfl_xor(a3, 32);
        if (eg == 0) {
            float4 o;
            o.x = a0 + bb.x; o.y = a1 + bb.y; o.z = a2 + bb.z; o.w = a3 + bb.w;
            *(float4*)(out + (size_t)(k * BROWS + r) * OUT_F + c4 * 4) = o;
        }
    }

    if (ntot > CAP) {   // overflow insurance (CAP is 22 sigma above the mean bucket size)
        __syncthreads();                          // out stores done; tmp dead
        for (int j = 0; j < L; ++j) {
            const int p = ofs + j;
            if (p >= CAP && p - CAP < CAP) tmp[p - CAP] = myrun[j];
        }
        __syncthreads();
        const int nov = min(ntot - CAP, CAP);
        for (int i = wid; i < nov; i += 4) {      // wave per edge, lane = column
            const uint2 ed = tmp[i];
            const float g = bf16_to_f32(support[(size_t)(ed.x & 0xFFFFFu) * OUT_F + lane]);
            atomicAdd(&out[(size_t)(k * BROWS + ((ed.x >> 20) & 31)) * OUT_F + lane],
                      g * __uint_as_float(ed.y));
        }
    }
}

// ---------------- Fallback (ws too small): gemm-only + bias-init + atomic scatter ----------
__global__ __launch_bounds__(256) void gemm_kernel(
    const float* __restrict__ x, const float* __restrict__ w,
    unsigned short* __restrict__ support) {
    __shared__ unsigned short b_lds[OUT_F * BK_PAD];
    const int t = threadIdx.x;
    #pragma unroll
    for (int i = 0; i < 8; ++i) {
        const int f = t + 256 * i;
        const int k = f >> 4, n4 = (f & 15) * 4;
        const float4 wv = ((const float4*)w)[f];
        b_lds[(n4 + 0) * BK_PAD + k] = f32_to_bf16(wv.x);
        b_lds[(n4 + 1) * BK_PAD + k] = f32_to_bf16(wv.y);
        b_lds[(n4 + 2) * BK_PAD + k] = f32_to_bf16(wv.z);
        b_lds[(n4 + 3) * BK_PAD + k] = f32_to_bf16(wv.w);
    }
    __syncthreads();
    const int lane = t & 63, wid = t >> 6;
    const int m16 = lane & 15, quad = lane >> 4;
    const int row0 = blockIdx.x * 64 + wid * 16;
    const int arow = min(row0 + m16, N_NODES - 1);
    const float* xr = x + (size_t)arow * IN_F;
    f32x4 acc[4];
    #pragma unroll
    for (int nt = 0; nt < 4; ++nt) acc[nt] = (f32x4){0.f, 0.f, 0.f, 0.f};
    #pragma unroll
    for (int kt = 0; kt < 4; ++kt) {
        const int kb = kt * 32 + quad * 8;
        const float4 a0 = *(const float4*)(xr + kb);
        const float4 a1 = *(const float4*)(xr + kb + 4);
        bf16x8 af;
        af[0] = (short)f32_to_bf16(a0.x); af[1] = (short)f32_to_bf16(a0.y);
        af[2] = (short)f32_to_bf16(a0.z); af[3] = (short)f32_to_bf16(a0.w);
        af[4] = (short)f32_to_bf16(a1.x); af[5] = (short)f32_to_bf16(a1.y);
        af[6] = (short)f32_to_bf16(a1.z); af[7] = (short)f32_to_bf16(a1.w);
        #pragma unroll
        for (int nt = 0; nt < 4; ++nt) {
            const bf16x8 bf = *(const bf16x8*)&b_lds[(nt * 16 + m16) * BK_PAD + kb];
            acc[nt] = __builtin_amdgcn_mfma_f32_16x16x32_bf16(af, bf, acc[nt], 0, 0, 0);
        }
    }
    #pragma unroll
    for (int nt = 0; nt < 4; ++nt) {
        #pragma unroll
        for (int r = 0; r < 4; ++r) {
            const int row = row0 + quad * 4 + r;
            if (row < N_NODES)
                support[(size_t)row * OUT_F + nt * 16 + m16] = f32_to_bf16(acc[nt][r]);
        }
    }
}
__global__ __launch_bounds__(256) void init_out_kernel(const float* __restrict__ bias,
                                                       float* __restrict__ out) {
    const size_t i = (size_t)blockIdx.x * 256 + threadIdx.x;
    if (i < (size_t)N_NODES * OUT_F) out[i] = bias[i & 63];
}
__global__ __launch_bounds__(256) void scatter_atomic_kernel(
    const unsigned short* __restrict__ support, const int* __restrict__ erow,
    const int* __restrict__ ecol, const float* __restrict__ evals,
    float* __restrict__ out) {
    const int wid = (blockIdx.x * 256 + threadIdx.x) >> 6;
    const int nw = gridDim.x * 4;
    const int lane = threadIdx.x & 63;
    const int n_iters = N_EDGES / 8;
    for (int it0 = wid; it0 < n_iters; it0 += nw) {
        const int e0 = __builtin_amdgcn_readfirstlane(it0) * 8;
        int src[8], dst[8]; float val[8];
        #pragma unroll
        for (int u = 0; u < 8; ++u) { src[u] = ecol[e0 + u]; dst[u] = erow[e0 + u]; val[u] = evals[e0 + u]; }
        float g[8];
        #pragma unroll
        for (int u = 0; u < 8; ++u) g[u] = bf16_to_f32(support[(size_t)src[u] * OUT_F + lane]);
        #pragma unroll
        for (int u = 0; u < 8; ++u) atomicAdd(&out[(size_t)dst[u] * OUT_F + lane], g[u] * val[u]);
    }
}

extern "C" void kernel_launch(void* const* d_in, const int* in_sizes, int n_in,
                              void* d_out, int out_size, void* d_ws, size_t ws_size,
                              hipStream_t stream) {
    const float* x     = (const float*)d_in[0];
    const float* w     = (const float*)d_in[1];
    const float* bias  = (const float*)d_in[2];
    const int* erow    = (const int*)d_in[3];
    const int* ecol    = (const int*)d_in[4];
    const float* evals = (const float*)d_in[5];
    float* out = (float*)d_out;

    char* p = (char*)d_ws;
    unsigned short* support = (unsigned short*)p;  size_t o = (size_t)N_NODES * OUT_F * 2;   // 12.8 MB
    int* pos_g = (int*)(p + o);                    o += (size_t)NCHUNK * NPOS * 4;            // 3.2 MB
    uint2* sedge = (uint2*)(p + o);                o += (size_t)N_EDGES * 8;                  // 12.8 MB

    if (ws_size >= o) {
        gemm_sort_kernel<<<NCHUNK + GEMM_BLKS, 512, 0, stream>>>(
            x, w, support, erow, ecol, evals, pos_g, sedge);
        gather_kernel<<<NBUCKET, 256, 0, stream>>>(support, sedge, pos_g, bias, out);
    } else {
        gemm_kernel<<<(N_NODES + 63) / 64, 256, 0, stream>>>(x, w, support);
        init_out_kernel<<<((N_NODES * OUT_F) + 255) / 256, 256, 0, stream>>>(bias, out);
        scatter_atomic_kernel<<<2048, 256, 0, stream>>>(support, erow, ecol, evals, out);
    }
}

// Round 7
// 161.308 us; speedup vs baseline: 1.0499x; 1.0499x over previous
//
#include <hip/hip_runtime.h>

#define N_NODES 100000
#define N_EDGES 1600000
#define IN_F 128
#define OUT_F 64

#define BROWS 32               // rows per bucket (100000 = 32 * 3125)
#define NBUCKET 3125
#define BK_PAD 136             // padded k-stride (shorts) for b_lds: breaks 16-way bank repeat

#define NCHUNK 512             // edge chunks; sort LDS = 37.5 KB -> 4 blocks/CU (full occ)
#define EPC (N_EDGES / NCHUNK) // 3125 edges per chunk (exact)
#define NPOS (NBUCKET + 1)     // 3126: per-chunk prefix incl. sentinel
#define GEMM_BLKS ((N_NODES + 127) / 128)   // 782: gemm sub-blocks (128 rows each)

#define SLOTS 40               // per-row segment capacity (mean 16, P(>40) ~ 2e-7)
#define NSPILL 128             // spill list (handles rows up to 40+128 edges)

typedef __attribute__((ext_vector_type(8))) short bf16x8;
typedef __attribute__((ext_vector_type(4))) float f32x4;

__device__ __forceinline__ unsigned short f32_to_bf16(float f) {
    const unsigned int b = __float_as_uint(f);
    return (unsigned short)((b + 0x7FFFu + ((b >> 16) & 1u)) >> 16);   // RNE
}
__device__ __forceinline__ float bf16_to_f32(unsigned short u) {
    return __uint_as_float(((unsigned int)u) << 16);
}
// unpack low/high bf16 of a uint32 (1 VALU each)
__device__ __forceinline__ float bflo(unsigned int u) { return __uint_as_float(u << 16); }
__device__ __forceinline__ float bfhi(unsigned int u) { return __uint_as_float(u & 0xFFFF0000u); }

// ---------------- Kernel 1: FUSED  gemm (blocks >= NCHUNK) + chunk-sort (blocks < NCHUNK) ----
// r5/r6 lesson: staged coalesced sedge writes (r5) beat direct scatter (r6, +8.7us),
// but r5's 62.6 KB union capped everything at 2 blocks/CU. Resolution: NCHUNK=512 ->
// EPC=3125 -> sd 25 KB + pos 12.5 KB = 37.5 KB union -> 4 x 512thr blocks/CU = 2048
// thr = FULL occupancy with staging intact.
//
// gemm: 512 thr = 8 waves; wave = 16 rows x 64 cols via MFMA 16x16x32 bf16. W transposed
// in LDS as [n][k] bf16 (pad 136) -> b-frags are ds_read_b128. Frag layouts
// (m89/m91-verified): A: m=lane&15,k=quad*8+j. B: n=lane&15,k=quad*8+j.
// C/D: col=lane&15, row=quad*4+r.
__global__ __launch_bounds__(512) void gemm_sort_kernel(
    const float* __restrict__ x, const float* __restrict__ w,
    unsigned short* __restrict__ support,
    const int* __restrict__ erow, const int* __restrict__ ecol,
    const float* __restrict__ evals, int* __restrict__ pos_g,
    uint2* __restrict__ sedge) {
    __shared__ union {
        struct { uint2 sd[EPC]; int pos[NPOS]; int wofs[8]; } s;   // 37.5 KB (sort)
        unsigned short b[OUT_F * BK_PAD];                          // 17.4 KB (gemm)
    } u;

    const int t = threadIdx.x;

    if (blockIdx.x < NCHUNK) {
        // ================= sort branch =================
        int* pos = u.s.pos;
        uint2* sd = u.s.sd;
        const int c = blockIdx.x;
        const size_t e0 = (size_t)c * EPC;

        for (int i = t; i < NPOS; i += 512) pos[i] = 0;
        __syncthreads();

        // pass 1: histogram (erow re-read in pass 2 is L2-hot: 12.5 KB slice/block)
        #pragma unroll 1
        for (int j = t; j < EPC; j += 512)
            atomicAdd(&pos[erow[e0 + j] >> 5], 1);
        __syncthreads();

        // block-exclusive scan over 3125 buckets, 7 per thread (512*7 = 3584 >= 3126)
        int v[7]; int s = 0;
        #pragma unroll
        for (int j = 0; j < 7; ++j) {
            const int i = t * 7 + j;
            v[j] = (i < NBUCKET) ? pos[i] : 0;
            s += v[j];
        }
        const int lane = t & 63, wid = t >> 6;
        int incl = s;
        #pragma unroll
        for (int d = 1; d < 64; d <<= 1) { int tv = __shfl_up(incl, d); if (lane >= d) incl += tv; }
        if (lane == 63) u.s.wofs[wid] = incl;
        __syncthreads();
        int wbase = 0;
        #pragma unroll
        for (int wj = 0; wj < 8; ++wj) wbase += (wj < wid) ? u.s.wofs[wj] : 0;
        int ex = wbase + incl - s;
        #pragma unroll
        for (int j = 0; j < 7; ++j) {
            const int i = t * 7 + j;
            if (i < NBUCKET) { pos[i] = ex; ex += v[j]; }   // own indices only: no hazard
        }
        if (t == 0) pos[NBUCKET] = EPC;
        __syncthreads();

        // persist per-chunk prefix (coalesced); gather reads it directly (L2-resident)
        int* pg = pos_g + (size_t)c * NPOS;
        for (int i = t; i < NPOS; i += 512) pg[i] = pos[i];
        __syncthreads();   // persist reads must finish before cursors mutate

        // pass 2: rank + scatter to LDS staging
        #pragma unroll 1
        for (int j = t; j < EPC; j += 512) {
            const int row = erow[e0 + j];
            const int col = ecol[e0 + j];
            const float val = evals[e0 + j];
            const int r = atomicAdd(&pos[row >> 5], 1);
            uint2 ed;
            ed.x = (unsigned int)col | (((unsigned int)row & 31u) << 20);
            ed.y = __float_as_uint(val);
            sd[r] = ed;
        }
        __syncthreads();

        // write sorted chunk, fully coalesced
        uint2* sg = sedge + e0;
        for (int i = t; i < EPC; i += 512) sg[i] = sd[i];
        return;
    }

    // ================= gemm branch =================
    const int bb = blockIdx.x - NCHUNK;
    // stage W transposed: w[k][n] (fp32, coalesced float4) -> b[n*BK_PAD + k] (bf16)
    #pragma unroll
    for (int i = 0; i < 4; ++i) {
        const int f = t + 512 * i;            // float4 index; k = f>>4, n4 = (f&15)*4
        const int k = f >> 4, n4 = (f & 15) * 4;
        const float4 wv = ((const float4*)w)[f];
        u.b[(n4 + 0) * BK_PAD + k] = f32_to_bf16(wv.x);
        u.b[(n4 + 1) * BK_PAD + k] = f32_to_bf16(wv.y);
        u.b[(n4 + 2) * BK_PAD + k] = f32_to_bf16(wv.z);
        u.b[(n4 + 3) * BK_PAD + k] = f32_to_bf16(wv.w);
    }
    __syncthreads();

    const int lane = t & 63, wid = t >> 6;
    const int m16 = lane & 15, quad = lane >> 4;
    const int row0 = bb * 128 + wid * 16;
    const int arow = min(row0 + m16, N_NODES - 1);
    const float* xr = x + (size_t)arow * IN_F;

    f32x4 acc[4];
    #pragma unroll
    for (int nt = 0; nt < 4; ++nt) acc[nt] = (f32x4){0.f, 0.f, 0.f, 0.f};

    #pragma unroll
    for (int kt = 0; kt < 4; ++kt) {
        const int kb = kt * 32 + quad * 8;
        const float4 a0 = *(const float4*)(xr + kb);
        const float4 a1 = *(const float4*)(xr + kb + 4);
        bf16x8 af;
        af[0] = (short)f32_to_bf16(a0.x); af[1] = (short)f32_to_bf16(a0.y);
        af[2] = (short)f32_to_bf16(a0.z); af[3] = (short)f32_to_bf16(a0.w);
        af[4] = (short)f32_to_bf16(a1.x); af[5] = (short)f32_to_bf16(a1.y);
        af[6] = (short)f32_to_bf16(a1.z); af[7] = (short)f32_to_bf16(a1.w);
        #pragma unroll
        for (int nt = 0; nt < 4; ++nt) {
            const bf16x8 bf = *(const bf16x8*)&u.b[(nt * 16 + m16) * BK_PAD + kb];
            acc[nt] = __builtin_amdgcn_mfma_f32_16x16x32_bf16(af, bf, acc[nt], 0, 0, 0);
        }
    }

    #pragma unroll
    for (int nt = 0; nt < 4; ++nt) {
        #pragma unroll
        for (int r = 0; r < 4; ++r) {
            const int row = row0 + quad * 4 + r;
            if (row < N_NODES)
                support[(size_t)row * OUT_F + nt * 16 + m16] = f32_to_bf16(acc[nt][r]);
        }
    }
}

// accumulate 8 edges (two quads) of one row into 4 col accumulators
#define QUAD8(A0, A1, A2, A3, J) do { \
    const uint2 q0 = sdata[(J) + eg], q1 = sdata[(J) + 4 + eg]; \
    const uint2 h0 = *(const uint2*)(support + (size_t)(q0.x & 0xFFFFFu) * OUT_F + c4 * 4); \
    const uint2 h1 = *(const uint2*)(support + (size_t)(q1.x & 0xFFFFFu) * OUT_F + c4 * 4); \
    const float w0 = __uint_as_float(q0.y), w1 = __uint_as_float(q1.y); \
    A0 += w0 * bflo(h0.x); A1 += w0 * bfhi(h0.x); A2 += w0 * bflo(h0.y); A3 += w0 * bfhi(h0.y); \
    A0 += w1 * bflo(h1.x); A1 += w1 * bfhi(h1.x); A2 += w1 * bflo(h1.y); A3 += w1 * bfhi(h1.y); \
} while (0)

// predicated quad tail (0..3 live edges of the 4-group)
#define QUADT(A0, A1, A2, A3, J, E) do { \
    const int jj = (J) + eg; const bool act = jj < (E); \
    const uint2 q = sdata[act ? jj : (J)]; \
    const float w = act ? __uint_as_float(q.y) : 0.f; \
    const uint2 h = *(const uint2*)(support + (size_t)(q.x & 0xFFFFFu) * OUT_F + c4 * 4); \
    A0 += w * bflo(h.x); A1 += w * bfhi(h.x); A2 += w * bflo(h.y); A3 += w * bfhi(h.y); \
} while (0)

// ---------------- Kernel 2: gather = one-pass segment placement + accumulation ---------------
// r6 moved every edge through LDS twice (tmp stash -> read -> count atomic -> place
// atomic -> sdata; 5 barriers). One-pass: fixed per-row segments sdata[row*40+slot],
// slot from ONE LDS atomicAdd; edge read once from (L2-hot) sedge, written once.
// 2 barriers, no tmp/scan/bptr machinery. SLOTS=40 (mean 16/row, P(>40) ~ 2e-7);
// spill list + post-store global-atomic fallback keeps pathological rows correct.
// Back-end unchanged (proven): 4 edge-groups x 16 lanes x 4 cols/lane, shfl_xor
// reduce, float4 store. Bijective XCD swizzle (m204) for sedge/pos_g L2 locality.
__global__ __launch_bounds__(256) void gather_kernel(
    const unsigned short* __restrict__ support, const uint2* __restrict__ sedge,
    const int* __restrict__ pos_g, const float* __restrict__ bias,
    float* __restrict__ out) {
    __shared__ uint2 sdata[BROWS * SLOTS];   // 10.2 KB row segments
    __shared__ uint2 spill[NSPILL];          // 1 KB (statistically never used)
    __shared__ int rcnt[BROWS];
    __shared__ int nspill;

    const int t = threadIdx.x;
    // nwg = 3125 = 8*390 + 5: xcd<5 owns 391 buckets, else 390 (bijective, m204)
    const int orig = blockIdx.x;
    const int xcd = orig & 7, loc = orig >> 3;
    const int k = (xcd < 5 ? xcd * 391 : 5 * 391 + (xcd - 5) * 390) + loc;
    const int lane = t & 63, wid = t >> 6;

    if (t < BROWS) rcnt[t] = 0;
    if (t == 0) nspill = 0;
    __syncthreads();

    // one-pass placement: thread t owns chunks t and t+256 (runs avg 1 edge each;
    // pos_g[c][k], pos_g[c][k+1] share a cache line; pos_g 6.4 MB -> L2-resident)
    #pragma unroll
    for (int cc = 0; cc < 2; ++cc) {
        const int c = t + cc * 256;
        const int s = pos_g[(size_t)c * NPOS + k];
        const int e = pos_g[(size_t)c * NPOS + k + 1];
        const uint2* run = sedge + (size_t)c * EPC;
        for (int j = s; j < e; ++j) {
            const uint2 ed = run[j];
            const int r = (ed.x >> 20) & 31;
            const int slot = atomicAdd(&rcnt[r], 1);
            if (slot < SLOTS) sdata[r * SLOTS + slot] = ed;
            else { const int q = atomicAdd(&nspill, 1); if (q < NSPILL) spill[q] = ed; }
        }
    }
    __syncthreads();

    const int eg = lane >> 4;          // edge-group 0..3
    const int c4 = lane & 15;          // col-quad: cols 4*c4 .. 4*c4+3
    const float4 bb = ((const float4*)bias)[c4];

    for (int r8 = 0; r8 < 8; ++r8) {
        const int r = wid * 8 + r8;
        const int cnt = min(rcnt[r], SLOTS);
        const int s0 = r * SLOTS, s1 = s0 + cnt;
        float a0 = 0.f, a1 = 0.f, a2 = 0.f, a3 = 0.f;
        int j = s0;
        for (; j + 8 <= s1; j += 8)              // 2 quads in flight
            QUAD8(a0, a1, a2, a3, j);
        for (; j < s1; j += 4)                   // predicated quad tail
            QUADT(a0, a1, a2, a3, j, s1);
        a0 += __shfl_xor(a0, 16); a0 += __shfl_xor(a0, 32);
        a1 += __shfl_xor(a1, 16); a1 += __shfl_xor(a1, 32);
        a2 += __shfl_xor(a2, 16); a2 += __shfl_xor(a2, 32);
        a3 += __shfl_xor(a3, 16); a3 += __shfl_xor(a3, 32);
        if (eg == 0) {
            float4 o;
            o.x = a0 + bb.x; o.y = a1 + bb.y; o.z = a2 + bb.z; o.w = a3 + bb.w;
            *(float4*)(out + (size_t)(k * BROWS + r) * OUT_F + c4 * 4) = o;
        }
    }

    if (nspill > 0) {   // insurance: rows with >SLOTS edges (P ~ 2e-7 per row)
        __syncthreads();                       // out stores drained (vmcnt@barrier)
        const int ns = min(nspill, NSPILL);
        for (int i = wid; i < ns; i += 4) {    // wave per edge, lane = column
            const uint2 ed = spill[i];
            const float g = bf16_to_f32(support[(size_t)(ed.x & 0xFFFFFu) * OUT_F + lane]);
            atomicAdd(&out[(size_t)(k * BROWS + ((ed.x >> 20) & 31)) * OUT_F + lane],
                      g * __uint_as_float(ed.y));
        }
    }
}

// ---------------- Fallback (ws too small): gemm-only + bias-init + atomic scatter ----------
__global__ __launch_bounds__(256) void gemm_kernel(
    const float* __restrict__ x, const float* __restrict__ w,
    unsigned short* __restrict__ support) {
    __shared__ unsigned short b_lds[OUT_F * BK_PAD];
    const int t = threadIdx.x;
    #pragma unroll
    for (int i = 0; i < 8; ++i) {
        const int f = t + 256 * i;
        const int k = f >> 4, n4 = (f & 15) * 4;
        const float4 wv = ((const float4*)w)[f];
        b_lds[(n4 + 0) * BK_PAD + k] = f32_to_bf16(wv.x);
        b_lds[(n4 + 1) * BK_PAD + k] = f32_to_bf16(wv.y);
        b_lds[(n4 + 2) * BK_PAD + k] = f32_to_bf16(wv.z);
        b_lds[(n4 + 3) * BK_PAD + k] = f32_to_bf16(wv.w);
    }
    __syncthreads();
    const int lane = t & 63, wid = t >> 6;
    const int m16 = lane & 15, quad = lane >> 4;
    const int row0 = blockIdx.x * 64 + wid * 16;
    const int arow = min(row0 + m16, N_NODES - 1);
    const float* xr = x + (size_t)arow * IN_F;
    f32x4 acc[4];
    #pragma unroll
    for (int nt = 0; nt < 4; ++nt) acc[nt] = (f32x4){0.f, 0.f, 0.f, 0.f};
    #pragma unroll
    for (int kt = 0; kt < 4; ++kt) {
        const int kb = kt * 32 + quad * 8;
        const float4 a0 = *(const float4*)(xr + kb);
        const float4 a1 = *(const float4*)(xr + kb + 4);
        bf16x8 af;
        af[0] = (short)f32_to_bf16(a0.x); af[1] = (short)f32_to_bf16(a0.y);
        af[2] = (short)f32_to_bf16(a0.z); af[3] = (short)f32_to_bf16(a0.w);
        af[4] = (short)f32_to_bf16(a1.x); af[5] = (short)f32_to_bf16(a1.y);
        af[6] = (short)f32_to_bf16(a1.z); af[7] = (short)f32_to_bf16(a1.w);
        #pragma unroll
        for (int nt = 0; nt < 4; ++nt) {
            const bf16x8 bf = *(const bf16x8*)&b_lds[(nt * 16 + m16) * BK_PAD + kb];
            acc[nt] = __builtin_amdgcn_mfma_f32_16x16x32_bf16(af, bf, acc[nt], 0, 0, 0);
        }
    }
    #pragma unroll
    for (int nt = 0; nt < 4; ++nt) {
        #pragma unroll
        for (int r = 0; r < 4; ++r) {
            const int row = row0 + quad * 4 + r;
            if (row < N_NODES)
                support[(size_t)row * OUT_F + nt * 16 + m16] = f32_to_bf16(acc[nt][r]);
        }
    }
}
__global__ __launch_bounds__(256) void init_out_kernel(const float* __restrict__ bias,
                                                       float* __restrict__ out) {
    const size_t i = (size_t)blockIdx.x * 256 + threadIdx.x;
    if (i < (size_t)N_NODES * OUT_F) out[i] = bias[i & 63];
}
__global__ __launch_bounds__(256) void scatter_atomic_kernel(
    const unsigned short* __restrict__ support, const int* __restrict__ erow,
    const int* __restrict__ ecol, const float* __restrict__ evals,
    float* __restrict__ out) {
    const int wid = (blockIdx.x * 256 + threadIdx.x) >> 6;
    const int nw = gridDim.x * 4;
    const int lane = threadIdx.x & 63;
    const int n_iters = N_EDGES / 8;
    for (int it0 = wid; it0 < n_iters; it0 += nw) {
        const int e0 = __builtin_amdgcn_readfirstlane(it0) * 8;
        int src[8], dst[8]; float val[8];
        #pragma unroll
        for (int u = 0; u < 8; ++u) { src[u] = ecol[e0 + u]; dst[u] = erow[e0 + u]; val[u] = evals[e0 + u]; }
        float g[8];
        #pragma unroll
        for (int u = 0; u < 8; ++u) g[u] = bf16_to_f32(support[(size_t)src[u] * OUT_F + lane]);
        #pragma unroll
        for (int u = 0; u < 8; ++u) atomicAdd(&out[(size_t)dst[u] * OUT_F + lane], g[u] * val[u]);
    }
}

extern "C" void kernel_launch(void* const* d_in, const int* in_sizes, int n_in,
                              void* d_out, int out_size, void* d_ws, size_t ws_size,
                              hipStream_t stream) {
    const float* x     = (const float*)d_in[0];
    const float* w     = (const float*)d_in[1];
    const float* bias  = (const float*)d_in[2];
    const int* erow    = (const int*)d_in[3];
    const int* ecol    = (const int*)d_in[4];
    const float* evals = (const float*)d_in[5];
    float* out = (float*)d_out;

    char* p = (char*)d_ws;
    unsigned short* support = (unsigned short*)p;  size_t o = (size_t)N_NODES * OUT_F * 2;   // 12.8 MB
    int* pos_g = (int*)(p + o);                    o += (size_t)NCHUNK * NPOS * 4;            // 6.4 MB
    uint2* sedge = (uint2*)(p + o);                o += (size_t)N_EDGES * 8;                  // 12.8 MB

    if (ws_size >= o) {
        gemm_sort_kernel<<<NCHUNK + GEMM_BLKS, 512, 0, stream>>>(
            x, w, support, erow, ecol, evals, pos_g, sedge);
        gather_kernel<<<NBUCKET, 256, 0, stream>>>(support, sedge, pos_g, bias, out);
    } else {
        gemm_kernel<<<(N_NODES + 63) / 64, 256, 0, stream>>>(x, w, support);
        init_out_kernel<<<((N_NODES * OUT_F) + 255) / 256, 256, 0, stream>>>(bias, out);
        scatter_atomic_kernel<<<2048, 256, 0, stream>>>(support, erow, ecol, evals, out);
    }
}

// Round 8
// 158.809 us; speedup vs baseline: 1.0664x; 1.0157x over previous
//
#include <hip/hip_runtime.h>

#define N_NODES 100000
#define N_EDGES 1600000
#define IN_F 128
#define OUT_F 64

#define BROWS 64               // rows per bucket (ceil(100000/64) = 1563 buckets)
#define NBUCKET 1563
#define BK_PAD 136             // padded k-stride (shorts) for b_lds: breaks 16-way bank repeat

#define NCHUNK 512             // edge chunks; sort LDS = 31.3 KB -> 5 blocks/CU
#define EPC (N_EDGES / NCHUNK) // 3125 edges per chunk (exact)
#define NPOS (NBUCKET + 1)     // 1564: per-chunk prefix incl. sentinel
#define GEMM_BLKS ((N_NODES + 127) / 128)   // 782: gemm sub-blocks (128 rows each)

#define SLOTS 40               // per-row segment capacity (mean 16, P(>40) ~ 4e-8)
#define NSPILL 128             // spill list (insurance)

typedef __attribute__((ext_vector_type(8))) short bf16x8;
typedef __attribute__((ext_vector_type(4))) float f32x4;

__device__ __forceinline__ unsigned short f32_to_bf16(float f) {
    const unsigned int b = __float_as_uint(f);
    return (unsigned short)((b + 0x7FFFu + ((b >> 16) & 1u)) >> 16);   // RNE
}
__device__ __forceinline__ float bf16_to_f32(unsigned short u) {
    return __uint_as_float(((unsigned int)u) << 16);
}
// unpack low/high bf16 of a uint32 (1 VALU each)
__device__ __forceinline__ float bflo(unsigned int u) { return __uint_as_float(u << 16); }
__device__ __forceinline__ float bfhi(unsigned int u) { return __uint_as_float(u & 0xFFFF0000u); }

// ---------------- Kernel 1: FUSED  gemm (blocks >= NCHUNK) + chunk-sort (blocks < NCHUNK) ----
// Staged coalesced sedge writes (r5/r6 lesson: beats direct scatter) at full occupancy:
// sd 25 KB + pos 6.3 KB (64-row buckets -> 1564 counters) = 31.3 KB union -> 5 blocks/CU.
//
// gemm: 512 thr = 8 waves; wave = 16 rows x 64 cols via MFMA 16x16x32 bf16. W transposed
// in LDS as [n][k] bf16 (pad 136) -> b-frags are ds_read_b128. Frag layouts
// (m89/m91-verified): A: m=lane&15,k=quad*8+j. B: n=lane&15,k=quad*8+j.
// C/D: col=lane&15, row=quad*4+r.
__global__ __launch_bounds__(512) void gemm_sort_kernel(
    const float* __restrict__ x, const float* __restrict__ w,
    unsigned short* __restrict__ support,
    const int* __restrict__ erow, const int* __restrict__ ecol,
    const float* __restrict__ evals, int* __restrict__ pos_g,
    uint2* __restrict__ sedge) {
    __shared__ union {
        struct { uint2 sd[EPC]; int pos[NPOS]; int wofs[8]; } s;   // 31.3 KB (sort)
        unsigned short b[OUT_F * BK_PAD];                          // 17.4 KB (gemm)
    } u;

    const int t = threadIdx.x;

    if (blockIdx.x < NCHUNK) {
        // ================= sort branch =================
        int* pos = u.s.pos;
        uint2* sd = u.s.sd;
        const int c = blockIdx.x;
        const size_t e0 = (size_t)c * EPC;

        for (int i = t; i < NPOS; i += 512) pos[i] = 0;
        __syncthreads();

        // pass 1: histogram over 64-row buckets (erow re-read in pass 2 is L2-hot)
        #pragma unroll 1
        for (int j = t; j < EPC; j += 512)
            atomicAdd(&pos[erow[e0 + j] >> 6], 1);
        __syncthreads();

        // block-exclusive scan over 1563 buckets, 4 per thread (512*4 = 2048 >= 1564)
        int v[4]; int s = 0;
        #pragma unroll
        for (int j = 0; j < 4; ++j) {
            const int i = t * 4 + j;
            v[j] = (i < NBUCKET) ? pos[i] : 0;
            s += v[j];
        }
        const int lane = t & 63, wid = t >> 6;
        int incl = s;
        #pragma unroll
        for (int d = 1; d < 64; d <<= 1) { int tv = __shfl_up(incl, d); if (lane >= d) incl += tv; }
        if (lane == 63) u.s.wofs[wid] = incl;
        __syncthreads();
        int wbase = 0;
        #pragma unroll
        for (int wj = 0; wj < 8; ++wj) wbase += (wj < wid) ? u.s.wofs[wj] : 0;
        int ex = wbase + incl - s;
        #pragma unroll
        for (int j = 0; j < 4; ++j) {
            const int i = t * 4 + j;
            if (i < NBUCKET) { pos[i] = ex; ex += v[j]; }   // own indices only: no hazard
        }
        if (t == 0) pos[NBUCKET] = EPC;
        __syncthreads();

        // persist per-chunk prefix (coalesced); gather reads it directly (L2-resident)
        int* pg = pos_g + (size_t)c * NPOS;
        for (int i = t; i < NPOS; i += 512) pg[i] = pos[i];
        __syncthreads();   // persist reads must finish before cursors mutate

        // pass 2: rank + scatter to LDS staging
        #pragma unroll 1
        for (int j = t; j < EPC; j += 512) {
            const int row = erow[e0 + j];
            const int col = ecol[e0 + j];
            const float val = evals[e0 + j];
            const int r = atomicAdd(&pos[row >> 6], 1);
            uint2 ed;
            ed.x = (unsigned int)col | (((unsigned int)row & 63u) << 20);
            ed.y = __float_as_uint(val);
            sd[r] = ed;
        }
        __syncthreads();

        // write sorted chunk, fully coalesced
        uint2* sg = sedge + e0;
        for (int i = t; i < EPC; i += 512) sg[i] = sd[i];
        return;
    }

    // ================= gemm branch =================
    const int bb = blockIdx.x - NCHUNK;
    // stage W transposed: w[k][n] (fp32, coalesced float4) -> b[n*BK_PAD + k] (bf16)
    #pragma unroll
    for (int i = 0; i < 4; ++i) {
        const int f = t + 512 * i;            // float4 index; k = f>>4, n4 = (f&15)*4
        const int k = f >> 4, n4 = (f & 15) * 4;
        const float4 wv = ((const float4*)w)[f];
        u.b[(n4 + 0) * BK_PAD + k] = f32_to_bf16(wv.x);
        u.b[(n4 + 1) * BK_PAD + k] = f32_to_bf16(wv.y);
        u.b[(n4 + 2) * BK_PAD + k] = f32_to_bf16(wv.z);
        u.b[(n4 + 3) * BK_PAD + k] = f32_to_bf16(wv.w);
    }
    __syncthreads();

    const int lane = t & 63, wid = t >> 6;
    const int m16 = lane & 15, quad = lane >> 4;
    const int row0 = bb * 128 + wid * 16;
    const int arow = min(row0 + m16, N_NODES - 1);
    const float* xr = x + (size_t)arow * IN_F;

    f32x4 acc[4];
    #pragma unroll
    for (int nt = 0; nt < 4; ++nt) acc[nt] = (f32x4){0.f, 0.f, 0.f, 0.f};

    #pragma unroll
    for (int kt = 0; kt < 4; ++kt) {
        const int kb = kt * 32 + quad * 8;
        const float4 a0 = *(const float4*)(xr + kb);
        const float4 a1 = *(const float4*)(xr + kb + 4);
        bf16x8 af;
        af[0] = (short)f32_to_bf16(a0.x); af[1] = (short)f32_to_bf16(a0.y);
        af[2] = (short)f32_to_bf16(a0.z); af[3] = (short)f32_to_bf16(a0.w);
        af[4] = (short)f32_to_bf16(a1.x); af[5] = (short)f32_to_bf16(a1.y);
        af[6] = (short)f32_to_bf16(a1.z); af[7] = (short)f32_to_bf16(a1.w);
        #pragma unroll
        for (int nt = 0; nt < 4; ++nt) {
            const bf16x8 bf = *(const bf16x8*)&u.b[(nt * 16 + m16) * BK_PAD + kb];
            acc[nt] = __builtin_amdgcn_mfma_f32_16x16x32_bf16(af, bf, acc[nt], 0, 0, 0);
        }
    }

    #pragma unroll
    for (int nt = 0; nt < 4; ++nt) {
        #pragma unroll
        for (int r = 0; r < 4; ++r) {
            const int row = row0 + quad * 4 + r;
            if (row < N_NODES)
                support[(size_t)row * OUT_F + nt * 16 + m16] = f32_to_bf16(acc[nt][r]);
        }
    }
}

// accumulate 8 edges (two quads) of one row into 4 col accumulators
#define QUAD8(A0, A1, A2, A3, J) do { \
    const uint2 q0 = sdata[(J) + eg], q1 = sdata[(J) + 4 + eg]; \
    const uint2 h0 = *(const uint2*)(support + (size_t)(q0.x & 0xFFFFFu) * OUT_F + c4 * 4); \
    const uint2 h1 = *(const uint2*)(support + (size_t)(q1.x & 0xFFFFFu) * OUT_F + c4 * 4); \
    const float w0 = __uint_as_float(q0.y), w1 = __uint_as_float(q1.y); \
    A0 += w0 * bflo(h0.x); A1 += w0 * bfhi(h0.x); A2 += w0 * bflo(h0.y); A3 += w0 * bfhi(h0.y); \
    A0 += w1 * bflo(h1.x); A1 += w1 * bfhi(h1.x); A2 += w1 * bflo(h1.y); A3 += w1 * bfhi(h1.y); \
} while (0)

// predicated quad tail (0..3 live edges of the 4-group)
#define QUADT(A0, A1, A2, A3, J, E) do { \
    const int jj = (J) + eg; const bool act = jj < (E); \
    const uint2 q = sdata[act ? jj : (J)]; \
    const float w = act ? __uint_as_float(q.y) : 0.f; \
    const uint2 h = *(const uint2*)(support + (size_t)(q.x & 0xFFFFFu) * OUT_F + c4 * 4); \
    A0 += w * bflo(h.x); A1 += w * bfhi(h.x); A2 += w * bflo(h.y); A3 += w * bfhi(h.y); \
} while (0)

// ---------------- Kernel 2: gather = one-pass segment placement + accumulation ---------------
// 64-row buckets (1024 edges avg), 512 threads: thread t = chunk t, ONE run (avg 2
// edges) per thread -> per-edge front-end cost half of r7's (512 runs per 1024 edges),
// pos_g descriptor traffic across grid halved (0.8M pair-reads), per-bucket fixed
// costs amortized 2x. Placement: fixed per-row segments sdata[row*40+slot], slot from
// one LDS atomicAdd; 2 barriers. Back-end unchanged (proven): 4 edge-groups x 16
// lanes x 4 cols/lane, shfl_xor reduce, float4 store; 8 rows per wave.
// Bijective XCD swizzle (1563 = 8*195+3) for sedge/pos_g L2 locality.
__global__ __launch_bounds__(512) void gather_kernel(
    const unsigned short* __restrict__ support, const uint2* __restrict__ sedge,
    const int* __restrict__ pos_g, const float* __restrict__ bias,
    float* __restrict__ out) {
    __shared__ uint2 sdata[BROWS * SLOTS];   // 20.5 KB row segments
    __shared__ uint2 spill[NSPILL];          // 1 KB (statistically never used)
    __shared__ int rcnt[BROWS];
    __shared__ int nspill;

    const int t = threadIdx.x;
    // nwg = 1563 = 8*195 + 3: xcd<3 owns 196 buckets, else 195 (bijective, m204)
    const int orig = blockIdx.x;
    const int xcd = orig & 7, loc = orig >> 3;
    const int k = (xcd < 3 ? xcd * 196 : 3 * 196 + (xcd - 3) * 195) + loc;
    const int lane = t & 63, wid = t >> 6;

    if (t < BROWS) rcnt[t] = 0;
    if (t == 0) nspill = 0;
    __syncthreads();

    // one-pass placement: thread t owns chunk t (pos_g[t][k], pos_g[t][k+1] share a
    // cache line; pos_g 3.2 MB -> L2-resident)
    {
        const int s = pos_g[(size_t)t * NPOS + k];
        const int e = pos_g[(size_t)t * NPOS + k + 1];
        const uint2* run = sedge + (size_t)t * EPC;
        for (int j = s; j < e; ++j) {
            const uint2 ed = run[j];
            const int r = (ed.x >> 20) & 63;
            const int slot = atomicAdd(&rcnt[r], 1);
            if (slot < SLOTS) sdata[r * SLOTS + slot] = ed;
            else { const int q = atomicAdd(&nspill, 1); if (q < NSPILL) spill[q] = ed; }
        }
    }
    __syncthreads();

    const int eg = lane >> 4;          // edge-group 0..3
    const int c4 = lane & 15;          // col-quad: cols 4*c4 .. 4*c4+3
    const float4 bb = ((const float4*)bias)[c4];

    for (int r8 = 0; r8 < 8; ++r8) {
        const int r = wid * 8 + r8;
        const int cnt = min(rcnt[r], SLOTS);
        const int s0 = r * SLOTS, s1 = s0 + cnt;
        float a0 = 0.f, a1 = 0.f, a2 = 0.f, a3 = 0.f;
        int j = s0;
        for (; j + 8 <= s1; j += 8)              // 2 quads in flight
            QUAD8(a0, a1, a2, a3, j);
        for (; j < s1; j += 4)                   // predicated quad tail
            QUADT(a0, a1, a2, a3, j, s1);
        a0 += __shfl_xor(a0, 16); a0 += __shfl_xor(a0, 32);
        a1 += __shfl_xor(a1, 16); a1 += __shfl_xor(a1, 32);
        a2 += __shfl_xor(a2, 16); a2 += __shfl_xor(a2, 32);
        a3 += __shfl_xor(a3, 16); a3 += __shfl_xor(a3, 32);
        const int node = k * BROWS + r;
        if (eg == 0 && node < N_NODES) {         // last bucket has 32 valid rows
            float4 o;
            o.x = a0 + bb.x; o.y = a1 + bb.y; o.z = a2 + bb.z; o.w = a3 + bb.w;
            *(float4*)(out + (size_t)node * OUT_F + c4 * 4) = o;
        }
    }

    if (nspill > 0) {   // insurance: rows with >SLOTS edges (P ~ 4e-8 per row)
        __syncthreads();                       // out stores drained (vmcnt@barrier)
        const int ns = min(nspill, NSPILL);
        for (int i = wid; i < ns; i += 8) {    // wave per edge, lane = column
            const uint2 ed = spill[i];
            const float g = bf16_to_f32(support[(size_t)(ed.x & 0xFFFFFu) * OUT_F + lane]);
            atomicAdd(&out[(size_t)(k * BROWS + ((ed.x >> 20) & 63)) * OUT_F + lane],
                      g * __uint_as_float(ed.y));
        }
    }
}

// ---------------- Fallback (ws too small): gemm-only + bias-init + atomic scatter ----------
__global__ __launch_bounds__(256) void gemm_kernel(
    const float* __restrict__ x, const float* __restrict__ w,
    unsigned short* __restrict__ support) {
    __shared__ unsigned short b_lds[OUT_F * BK_PAD];
    const int t = threadIdx.x;
    #pragma unroll
    for (int i = 0; i < 8; ++i) {
        const int f = t + 256 * i;
        const int k = f >> 4, n4 = (f & 15) * 4;
        const float4 wv = ((const float4*)w)[f];
        b_lds[(n4 + 0) * BK_PAD + k] = f32_to_bf16(wv.x);
        b_lds[(n4 + 1) * BK_PAD + k] = f32_to_bf16(wv.y);
        b_lds[(n4 + 2) * BK_PAD + k] = f32_to_bf16(wv.z);
        b_lds[(n4 + 3) * BK_PAD + k] = f32_to_bf16(wv.w);
    }
    __syncthreads();
    const int lane = t & 63, wid = t >> 6;
    const int m16 = lane & 15, quad = lane >> 4;
    const int row0 = blockIdx.x * 64 + wid * 16;
    const int arow = min(row0 + m16, N_NODES - 1);
    const float* xr = x + (size_t)arow * IN_F;
    f32x4 acc[4];
    #pragma unroll
    for (int nt = 0; nt < 4; ++nt) acc[nt] = (f32x4){0.f, 0.f, 0.f, 0.f};
    #pragma unroll
    for (int kt = 0; kt < 4; ++kt) {
        const int kb = kt * 32 + quad * 8;
        const float4 a0 = *(const float4*)(xr + kb);
        const float4 a1 = *(const float4*)(xr + kb + 4);
        bf16x8 af;
        af[0] = (short)f32_to_bf16(a0.x); af[1] = (short)f32_to_bf16(a0.y);
        af[2] = (short)f32_to_bf16(a0.z); af[3] = (short)f32_to_bf16(a0.w);
        af[4] = (short)f32_to_bf16(a1.x); af[5] = (short)f32_to_bf16(a1.y);
        af[6] = (short)f32_to_bf16(a1.z); af[7] = (short)f32_to_bf16(a1.w);
        #pragma unroll
        for (int nt = 0; nt < 4; ++nt) {
            const bf16x8 bf = *(const bf16x8*)&b_lds[(nt * 16 + m16) * BK_PAD + kb];
            acc[nt] = __builtin_amdgcn_mfma_f32_16x16x32_bf16(af, bf, acc[nt], 0, 0, 0);
        }
    }
    #pragma unroll
    for (int nt = 0; nt < 4; ++nt) {
        #pragma unroll
        for (int r = 0; r < 4; ++r) {
            const int row = row0 + quad * 4 + r;
            if (row < N_NODES)
                support[(size_t)row * OUT_F + nt * 16 + m16] = f32_to_bf16(acc[nt][r]);
        }
    }
}
__global__ __launch_bounds__(256) void init_out_kernel(const float* __restrict__ bias,
                                                       float* __restrict__ out) {
    const size_t i = (size_t)blockIdx.x * 256 + threadIdx.x;
    if (i < (size_t)N_NODES * OUT_F) out[i] = bias[i & 63];
}
__global__ __launch_bounds__(256) void scatter_atomic_kernel(
    const unsigned short* __restrict__ support, const int* __restrict__ erow,
    const int* __restrict__ ecol, const float* __restrict__ evals,
    float* __restrict__ out) {
    const int wid = (blockIdx.x * 256 + threadIdx.x) >> 6;
    const int nw = gridDim.x * 4;
    const int lane = threadIdx.x & 63;
    const int n_iters = N_EDGES / 8;
    for (int it0 = wid; it0 < n_iters; it0 += nw) {
        const int e0 = __builtin_amdgcn_readfirstlane(it0) * 8;
        int src[8], dst[8]; float val[8];
        #pragma unroll
        for (int u = 0; u < 8; ++u) { src[u] = ecol[e0 + u]; dst[u] = erow[e0 + u]; val[u] = evals[e0 + u]; }
        float g[8];
        #pragma unroll
        for (int u = 0; u < 8; ++u) g[u] = bf16_to_f32(support[(size_t)src[u] * OUT_F + lane]);
        #pragma unroll
        for (int u = 0; u < 8; ++u) atomicAdd(&out[(size_t)dst[u] * OUT_F + lane], g[u] * val[u]);
    }
}

extern "C" void kernel_launch(void* const* d_in, const int* in_sizes, int n_in,
                              void* d_out, int out_size, void* d_ws, size_t ws_size,
                              hipStream_t stream) {
    const float* x     = (const float*)d_in[0];
    const float* w     = (const float*)d_in[1];
    const float* bias  = (const float*)d_in[2];
    const int* erow    = (const int*)d_in[3];
    const int* ecol    = (const int*)d_in[4];
    const float* evals = (const float*)d_in[5];
    float* out = (float*)d_out;

    char* p = (char*)d_ws;
    unsigned short* support = (unsigned short*)p;  size_t o = (size_t)N_NODES * OUT_F * 2;   // 12.8 MB
    int* pos_g = (int*)(p + o);                    o += (size_t)NCHUNK * NPOS * 4;            // 3.2 MB
    uint2* sedge = (uint2*)(p + o);                o += (size_t)N_EDGES * 8;                  // 12.8 MB

    if (ws_size >= o) {
        gemm_sort_kernel<<<NCHUNK + GEMM_BLKS, 512, 0, stream>>>(
            x, w, support, erow, ecol, evals, pos_g, sedge);
        gather_kernel<<<NBUCKET, 512, 0, stream>>>(support, sedge, pos_g, bias, out);
    } else {
        gemm_kernel<<<(N_NODES + 63) / 64, 256, 0, stream>>>(x, w, support);
        init_out_kernel<<<((N_NODES * OUT_F) + 255) / 256, 256, 0, stream>>>(bias, out);
        scatter_atomic_kernel<<<2048, 256, 0, stream>>>(support, erow, ecol, evals, out);
    }
}

// Round 10
// 155.762 us; speedup vs baseline: 1.0873x; 1.0196x over previous
//
#include <hip/hip_runtime.h>

#define N_NODES 100000
#define N_EDGES 1600000
#define IN_F 128
#define OUT_F 64

#define BROWS 64               // rows per bucket (ceil(100000/64) = 1563 buckets)
#define NBUCKET 1563
#define BK_PAD 136             // padded k-stride (shorts) for b_lds: breaks 16-way bank repeat

#define NCHUNK 512             // edge chunks; sort LDS = 31.3 KB -> 5 blocks/CU
#define EPC (N_EDGES / NCHUNK) // 3125 edges per chunk (exact)
#define NPOS (NBUCKET + 1)     // 1564: per-chunk prefix incl. sentinel
#define GEMM_BLKS ((N_NODES + 127) / 128)   // 782: gemm sub-blocks (128 rows each)

#define SLOTS 40               // per-row segment capacity (mean 16, P(>40) ~ 4e-8)
#define NSPILL 128             // spill list (insurance)

typedef __attribute__((ext_vector_type(8))) short bf16x8;
typedef __attribute__((ext_vector_type(4))) float f32x4;

__device__ __forceinline__ unsigned short f32_to_bf16(float f) {
    const unsigned int b = __float_as_uint(f);
    return (unsigned short)((b + 0x7FFFu + ((b >> 16) & 1u)) >> 16);   // RNE
}
__device__ __forceinline__ float bf16_to_f32(unsigned short u) {
    return __uint_as_float(((unsigned int)u) << 16);
}
// unpack low/high bf16 of a uint32 (1 VALU each)
__device__ __forceinline__ float bflo(unsigned int u) { return __uint_as_float(u << 16); }
__device__ __forceinline__ float bfhi(unsigned int u) { return __uint_as_float(u & 0xFFFF0000u); }

// ---------------- Kernel 1: FUSED  gemm (blocks >= NCHUNK) + chunk-sort (blocks < NCHUNK) ----
// Staged coalesced sedge writes (r5/r6 lesson: beats direct scatter) at full occupancy:
// sd 25 KB + pos 6.3 KB (64-row buckets -> 1564 counters) = 31.3 KB union -> 5 blocks/CU.
//
// gemm: 512 thr = 8 waves; wave = 16 rows x 64 cols via MFMA 16x16x32 bf16. W transposed
// in LDS as [n][k] bf16 (pad 136) -> b-frags are ds_read_b128. Frag layouts
// (m89/m91-verified): A: m=lane&15,k=quad*8+j. B: n=lane&15,k=quad*8+j.
// C/D: col=lane&15, row=quad*4+r.
__global__ __launch_bounds__(512) void gemm_sort_kernel(
    const float* __restrict__ x, const float* __restrict__ w,
    unsigned short* __restrict__ support,
    const int* __restrict__ erow, const int* __restrict__ ecol,
    const float* __restrict__ evals, int* __restrict__ pos_g,
    uint2* __restrict__ sedge) {
    __shared__ union {
        struct { uint2 sd[EPC]; int pos[NPOS]; int wofs[8]; } s;   // 31.3 KB (sort)
        unsigned short b[OUT_F * BK_PAD];                          // 17.4 KB (gemm)
    } u;

    const int t = threadIdx.x;

    if (blockIdx.x < NCHUNK) {
        // ================= sort branch =================
        int* pos = u.s.pos;
        uint2* sd = u.s.sd;
        const int c = blockIdx.x;
        const size_t e0 = (size_t)c * EPC;

        for (int i = t; i < NPOS; i += 512) pos[i] = 0;
        __syncthreads();

        // pass 1: histogram over 64-row buckets (erow re-read in pass 2 is L2-hot)
        #pragma unroll 1
        for (int j = t; j < EPC; j += 512)
            atomicAdd(&pos[erow[e0 + j] >> 6], 1);
        __syncthreads();

        // block-exclusive scan over 1563 buckets, 4 per thread (512*4 = 2048 >= 1564)
        int v[4]; int s = 0;
        #pragma unroll
        for (int j = 0; j < 4; ++j) {
            const int i = t * 4 + j;
            v[j] = (i < NBUCKET) ? pos[i] : 0;
            s += v[j];
        }
        const int lane = t & 63, wid = t >> 6;
        int incl = s;
        #pragma unroll
        for (int d = 1; d < 64; d <<= 1) { int tv = __shfl_up(incl, d); if (lane >= d) incl += tv; }
        if (lane == 63) u.s.wofs[wid] = incl;
        __syncthreads();
        int wbase = 0;
        #pragma unroll
        for (int wj = 0; wj < 8; ++wj) wbase += (wj < wid) ? u.s.wofs[wj] : 0;
        int ex = wbase + incl - s;
        #pragma unroll
        for (int j = 0; j < 4; ++j) {
            const int i = t * 4 + j;
            if (i < NBUCKET) { pos[i] = ex; ex += v[j]; }   // own indices only: no hazard
        }
        if (t == 0) pos[NBUCKET] = EPC;
        __syncthreads();

        // persist per-chunk prefix (coalesced); gather reads it directly (L2-resident)
        int* pg = pos_g + (size_t)c * NPOS;
        for (int i = t; i < NPOS; i += 512) pg[i] = pos[i];
        __syncthreads();   // persist reads must finish before cursors mutate

        // pass 2: rank + scatter to LDS staging
        #pragma unroll 1
        for (int j = t; j < EPC; j += 512) {
            const int row = erow[e0 + j];
            const int col = ecol[e0 + j];
            const float val = evals[e0 + j];
            const int r = atomicAdd(&pos[row >> 6], 1);
            uint2 ed;
            ed.x = (unsigned int)col | (((unsigned int)row & 63u) << 20);
            ed.y = __float_as_uint(val);
            sd[r] = ed;
        }
        __syncthreads();

        // write sorted chunk, fully coalesced
        uint2* sg = sedge + e0;
        for (int i = t; i < EPC; i += 512) sg[i] = sd[i];
        return;
    }

    // ================= gemm branch =================
    const int bb = blockIdx.x - NCHUNK;
    // stage W transposed: w[k][n] (fp32, coalesced float4) -> b[n*BK_PAD + k] (bf16)
    #pragma unroll
    for (int i = 0; i < 4; ++i) {
        const int f = t + 512 * i;            // float4 index; k = f>>4, n4 = (f&15)*4
        const int k = f >> 4, n4 = (f & 15) * 4;
        const float4 wv = ((const float4*)w)[f];
        u.b[(n4 + 0) * BK_PAD + k] = f32_to_bf16(wv.x);
        u.b[(n4 + 1) * BK_PAD + k] = f32_to_bf16(wv.y);
        u.b[(n4 + 2) * BK_PAD + k] = f32_to_bf16(wv.z);
        u.b[(n4 + 3) * BK_PAD + k] = f32_to_bf16(wv.w);
    }
    __syncthreads();

    const int lane = t & 63, wid = t >> 6;
    const int m16 = lane & 15, quad = lane >> 4;
    const int row0 = bb * 128 + wid * 16;
    const int arow = min(row0 + m16, N_NODES - 1);
    const float* xr = x + (size_t)arow * IN_F;

    f32x4 acc[4];
    #pragma unroll
    for (int nt = 0; nt < 4; ++nt) acc[nt] = (f32x4){0.f, 0.f, 0.f, 0.f};

    #pragma unroll
    for (int kt = 0; kt < 4; ++kt) {
        const int kb = kt * 32 + quad * 8;
        const float4 a0 = *(const float4*)(xr + kb);
        const float4 a1 = *(const float4*)(xr + kb + 4);
        bf16x8 af;
        af[0] = (short)f32_to_bf16(a0.x); af[1] = (short)f32_to_bf16(a0.y);
        af[2] = (short)f32_to_bf16(a0.z); af[3] = (short)f32_to_bf16(a0.w);
        af[4] = (short)f32_to_bf16(a1.x); af[5] = (short)f32_to_bf16(a1.y);
        af[6] = (short)f32_to_bf16(a1.z); af[7] = (short)f32_to_bf16(a1.w);
        #pragma unroll
        for (int nt = 0; nt < 4; ++nt) {
            const bf16x8 bf = *(const bf16x8*)&u.b[(nt * 16 + m16) * BK_PAD + kb];
            acc[nt] = __builtin_amdgcn_mfma_f32_16x16x32_bf16(af, bf, acc[nt], 0, 0, 0);
        }
    }

    #pragma unroll
    for (int nt = 0; nt < 4; ++nt) {
        #pragma unroll
        for (int r = 0; r < 4; ++r) {
            const int row = row0 + quad * 4 + r;
            if (row < N_NODES)
                support[(size_t)row * OUT_F + nt * 16 + m16] = f32_to_bf16(acc[nt][r]);
        }
    }
}

// 16 edges (four quads) of one row: 4 independent sdata reads + 4 support gathers in flight
#define QUAD16(A0, A1, A2, A3, J) do { \
    const uint2 q0 = sdata[(J) + eg],      q1 = sdata[(J) + 4 + eg]; \
    const uint2 q2 = sdata[(J) + 8 + eg],  q3 = sdata[(J) + 12 + eg]; \
    const uint2 h0 = *(const uint2*)(support + (size_t)(q0.x & 0xFFFFFu) * OUT_F + c4 * 4); \
    const uint2 h1 = *(const uint2*)(support + (size_t)(q1.x & 0xFFFFFu) * OUT_F + c4 * 4); \
    const uint2 h2 = *(const uint2*)(support + (size_t)(q2.x & 0xFFFFFu) * OUT_F + c4 * 4); \
    const uint2 h3 = *(const uint2*)(support + (size_t)(q3.x & 0xFFFFFu) * OUT_F + c4 * 4); \
    const float w0 = __uint_as_float(q0.y), w1 = __uint_as_float(q1.y); \
    const float w2 = __uint_as_float(q2.y), w3 = __uint_as_float(q3.y); \
    A0 += w0 * bflo(h0.x); A1 += w0 * bfhi(h0.x); A2 += w0 * bflo(h0.y); A3 += w0 * bfhi(h0.y); \
    A0 += w1 * bflo(h1.x); A1 += w1 * bfhi(h1.x); A2 += w1 * bflo(h1.y); A3 += w1 * bfhi(h1.y); \
    A0 += w2 * bflo(h2.x); A1 += w2 * bfhi(h2.x); A2 += w2 * bflo(h2.y); A3 += w2 * bfhi(h2.y); \
    A0 += w3 * bflo(h3.x); A1 += w3 * bfhi(h3.x); A2 += w3 * bflo(h3.y); A3 += w3 * bfhi(h3.y); \
} while (0)

// 8 edges (two quads), 2 gathers in flight
#define QUAD8(A0, A1, A2, A3, J) do { \
    const uint2 q0 = sdata[(J) + eg], q1 = sdata[(J) + 4 + eg]; \
    const uint2 h0 = *(const uint2*)(support + (size_t)(q0.x & 0xFFFFFu) * OUT_F + c4 * 4); \
    const uint2 h1 = *(const uint2*)(support + (size_t)(q1.x & 0xFFFFFu) * OUT_F + c4 * 4); \
    const float w0 = __uint_as_float(q0.y), w1 = __uint_as_float(q1.y); \
    A0 += w0 * bflo(h0.x); A1 += w0 * bfhi(h0.x); A2 += w0 * bflo(h0.y); A3 += w0 * bfhi(h0.y); \
    A0 += w1 * bflo(h1.x); A1 += w1 * bfhi(h1.x); A2 += w1 * bflo(h1.y); A3 += w1 * bfhi(h1.y); \
} while (0)

// predicated quad tail (0..3 live edges of the 4-group)
#define QUADT(A0, A1, A2, A3, J, E) do { \
    const int jj = (J) + eg; const bool act = jj < (E); \
    const uint2 q = sdata[act ? jj : (J)]; \
    const float w = act ? __uint_as_float(q.y) : 0.f; \
    const uint2 h = *(const uint2*)(support + (size_t)(q.x & 0xFFFFFu) * OUT_F + c4 * 4); \
    A0 += w * bflo(h.x); A1 += w * bfhi(h.x); A2 += w * bflo(h.y); A3 += w * bfhi(h.y); \
} while (0)

// place one edge into its row segment
#define PLACE(ED) do { \
    const int r_ = ((ED).x >> 20) & 63; \
    const int sl_ = atomicAdd(&rcnt[r_], 1); \
    if (sl_ < SLOTS) sdata[r_ * SLOTS + sl_] = (ED); \
    else { const int q_ = atomicAdd(&nspill, 1); if (q_ < NSPILL) spill[q_] = (ED); } \
} while (0)

// ---------------- Kernel 2: gather = one-pass segment placement + accumulation ---------------
// r8 structure (proven best) with MLP deepened to match the latency-bound regime
// (r8: VGPR=20 -> only 2 gathers in flight; budget at 8 waves/SIMD is 64 VGPR):
//  - front-end: 4-deep batched run-load head (P(run<=4) ~ 95%), 2-deep tail — collapses
//    the serial load->atomic->store chain from L round trips to ~1;
//  - back-end: QUAD16 = 4 independent support gathers in flight (row mean = 16 edges
//    -> common case is exactly one QUAD16), QUAD8/QUADT tails.
// Bijective XCD swizzle (1563 = 8*195+3) for sedge/pos_g L2 locality.
__global__ __launch_bounds__(512) void gather_kernel(
    const unsigned short* __restrict__ support, const uint2* __restrict__ sedge,
    const int* __restrict__ pos_g, const float* __restrict__ bias,
    float* __restrict__ out) {
    __shared__ uint2 sdata[BROWS * SLOTS];   // 20.5 KB row segments
    __shared__ uint2 spill[NSPILL];          // 1 KB (statistically never used)
    __shared__ int rcnt[BROWS];
    __shared__ int nspill;

    const int t = threadIdx.x;
    // nwg = 1563 = 8*195 + 3: xcd<3 owns 196 buckets, else 195 (bijective, m204)
    const int orig = blockIdx.x;
    const int xcd = orig & 7, loc = orig >> 3;
    const int k = (xcd < 3 ? xcd * 196 : 3 * 196 + (xcd - 3) * 195) + loc;
    const int lane = t & 63, wid = t >> 6;

    if (t < BROWS) rcnt[t] = 0;
    if (t == 0) nspill = 0;
    __syncthreads();

    // one-pass placement: thread t owns chunk t (pos_g[t][k], pos_g[t][k+1] share a
    // cache line; pos_g 3.2 MB -> L2-resident). 4-deep batched load head.
    {
        const int s = pos_g[(size_t)t * NPOS + k];
        const int e = pos_g[(size_t)t * NPOS + k + 1];
        const int L = e - s;
        const uint2* run = sedge + (size_t)t * EPC;
        uint2 b0, b1, b2, b3;
        if (L > 0) b0 = run[s];
        if (L > 1) b1 = run[s + 1];
        if (L > 2) b2 = run[s + 2];
        if (L > 3) b3 = run[s + 3];
        if (L > 0) PLACE(b0);
        if (L > 1) PLACE(b1);
        if (L > 2) PLACE(b2);
        if (L > 3) PLACE(b3);
        #pragma unroll 1
        for (int j = s + 4; j < e; j += 2) {     // rare tail (P ~ 5%), 2-deep
            uint2 c0 = run[j]; uint2 c1;
            const bool h2 = (j + 1) < e;
            if (h2) c1 = run[j + 1];
            PLACE(c0);
            if (h2) PLACE(c1);
        }
    }
    __syncthreads();

    const int eg = lane >> 4;          // edge-group 0..3
    const int c4 = lane & 15;          // col-quad: cols 4*c4 .. 4*c4+3
    const float4 bb = ((const float4*)bias)[c4];

    for (int r8 = 0; r8 < 8; ++r8) {
        const int r = wid * 8 + r8;
        const int cnt = min(rcnt[r], SLOTS);
        const int s0 = r * SLOTS, s1 = s0 + cnt;
        float a0 = 0.f, a1 = 0.f, a2 = 0.f, a3 = 0.f;
        int j = s0;
        for (; j + 16 <= s1; j += 16)            // 4 gathers in flight
            QUAD16(a0, a1, a2, a3, j);
        if (j + 8 <= s1) { QUAD8(a0, a1, a2, a3, j); j += 8; }
        for (; j < s1; j += 4)                   // predicated quad tail
            QUADT(a0, a1, a2, a3, j, s1);
        a0 += __shfl_xor(a0, 16); a0 += __shfl_xor(a0, 32);
        a1 += __shfl_xor(a1, 16); a1 += __shfl_xor(a1, 32);
        a2 += __shfl_xor(a2, 16); a2 += __shfl_xor(a2, 32);
        a3 += __shfl_xor(a3, 16); a3 += __shfl_xor(a3, 32);
        const int node = k * BROWS + r;
        if (eg == 0 && node < N_NODES) {         // last bucket has 32 valid rows
            float4 o;
            o.x = a0 + bb.x; o.y = a1 + bb.y; o.z = a2 + bb.z; o.w = a3 + bb.w;
            *(float4*)(out + (size_t)node * OUT_F + c4 * 4) = o;
        }
    }

    if (nspill > 0) {   // insurance: rows with >SLOTS edges (P ~ 4e-8 per row)
        __syncthreads();                       // out stores drained (vmcnt@barrier)
        const int ns = min(nspill, NSPILL);
        for (int i = wid; i < ns; i += 8) {    // wave per edge, lane = column
            const uint2 ed = spill[i];
            const float g = bf16_to_f32(support[(size_t)(ed.x & 0xFFFFFu) * OUT_F + lane]);
            atomicAdd(&out[(size_t)(k * BROWS + ((ed.x >> 20) & 63)) * OUT_F + lane],
                      g * __uint_as_float(ed.y));
        }
    }
}

// ---------------- Fallback (ws too small): gemm-only + bias-init + atomic scatter ----------
__global__ __launch_bounds__(256) void gemm_kernel(
    const float* __restrict__ x, const float* __restrict__ w,
    unsigned short* __restrict__ support) {
    __shared__ unsigned short b_lds[OUT_F * BK_PAD];
    const int t = threadIdx.x;
    #pragma unroll
    for (int i = 0; i < 8; ++i) {
        const int f = t + 256 * i;
        const int k = f >> 4, n4 = (f & 15) * 4;
        const float4 wv = ((const float4*)w)[f];
        b_lds[(n4 + 0) * BK_PAD + k] = f32_to_bf16(wv.x);
        b_lds[(n4 + 1) * BK_PAD + k] = f32_to_bf16(wv.y);
        b_lds[(n4 + 2) * BK_PAD + k] = f32_to_bf16(wv.z);
        b_lds[(n4 + 3) * BK_PAD + k] = f32_to_bf16(wv.w);
    }
    __syncthreads();
    const int lane = t & 63, wid = t >> 6;
    const int m16 = lane & 15, quad = lane >> 4;
    const int row0 = blockIdx.x * 64 + wid * 16;
    const int arow = min(row0 + m16, N_NODES - 1);
    const float* xr = x + (size_t)arow * IN_F;
    f32x4 acc[4];
    #pragma unroll
    for (int nt = 0; nt < 4; ++nt) acc[nt] = (f32x4){0.f, 0.f, 0.f, 0.f};
    #pragma unroll
    for (int kt = 0; kt < 4; ++kt) {
        const int kb = kt * 32 + quad * 8;
        const float4 a0 = *(const float4*)(xr + kb);
        const float4 a1 = *(const float4*)(xr + kb + 4);
        bf16x8 af;
        af[0] = (short)f32_to_bf16(a0.x); af[1] = (short)f32_to_bf16(a0.y);
        af[2] = (short)f32_to_bf16(a0.z); af[3] = (short)f32_to_bf16(a0.w);
        af[4] = (short)f32_to_bf16(a1.x); af[5] = (short)f32_to_bf16(a1.y);
        af[6] = (short)f32_to_bf16(a1.z); af[7] = (short)f32_to_bf16(a1.w);
        #pragma unroll
        for (int nt = 0; nt < 4; ++nt) {
            const bf16x8 bf = *(const bf16x8*)&b_lds[(nt * 16 + m16) * BK_PAD + kb];
            acc[nt] = __builtin_amdgcn_mfma_f32_16x16x32_bf16(af, bf, acc[nt], 0, 0, 0);
        }
    }
    #pragma unroll
    for (int nt = 0; nt < 4; ++nt) {
        #pragma unroll
        for (int r = 0; r < 4; ++r) {
            const int row = row0 + quad * 4 + r;
            if (row < N_NODES)
                support[(size_t)row * OUT_F + nt * 16 + m16] = f32_to_bf16(acc[nt][r]);
        }
    }
}
__global__ __launch_bounds__(256) void init_out_kernel(const float* __restrict__ bias,
                                                       float* __restrict__ out) {
    const size_t i = (size_t)blockIdx.x * 256 + threadIdx.x;
    if (i < (size_t)N_NODES * OUT_F) out[i] = bias[i & 63];
}
__global__ __launch_bounds__(256) void scatter_atomic_kernel(
    const unsigned short* __restrict__ support, const int* __restrict__ erow,
    const int* __restrict__ ecol, const float* __restrict__ evals,
    float* __restrict__ out) {
    const int wid = (blockIdx.x * 256 + threadIdx.x) >> 6;
    const int nw = gridDim.x * 4;
    const int lane = threadIdx.x & 63;
    const int n_iters = N_EDGES / 8;
    for (int it0 = wid; it0 < n_iters; it0 += nw) {
        const int e0 = __builtin_amdgcn_readfirstlane(it0) * 8;
        int src[8], dst[8]; float val[8];
        #pragma unroll
        for (int u = 0; u < 8; ++u) { src[u] = ecol[e0 + u]; dst[u] = erow[e0 + u]; val[u] = evals[e0 + u]; }
        float g[8];
        #pragma unroll
        for (int u = 0; u < 8; ++u) g[u] = bf16_to_f32(support[(size_t)src[u] * OUT_F + lane]);
        #pragma unroll
        for (int u = 0; u < 8; ++u) atomicAdd(&out[(size_t)dst[u] * OUT_F + lane], g[u] * val[u]);
    }
}

extern "C" void kernel_launch(void* const* d_in, const int* in_sizes, int n_in,
                              void* d_out, int out_size, void* d_ws, size_t ws_size,
                              hipStream_t stream) {
    const float* x     = (const float*)d_in[0];
    const float* w     = (const float*)d_in[1];
    const float* bias  = (const float*)d_in[2];
    const int* erow    = (const int*)d_in[3];
    const int* ecol    = (const int*)d_in[4];
    const float* evals = (const float*)d_in[5];
    float* out = (float*)d_out;

    char* p = (char*)d_ws;
    unsigned short* support = (unsigned short*)p;  size_t o = (size_t)N_NODES * OUT_F * 2;   // 12.8 MB
    int* pos_g = (int*)(p + o);                    o += (size_t)NCHUNK * NPOS * 4;            // 3.2 MB
    uint2* sedge = (uint2*)(p + o);                o += (size_t)N_EDGES * 8;                  // 12.8 MB

    if (ws_size >= o) {
        gemm_sort_kernel<<<NCHUNK + GEMM_BLKS, 512, 0, stream>>>(
            x, w, support, erow, ecol, evals, pos_g, sedge);
        gather_kernel<<<NBUCKET, 512, 0, stream>>>(support, sedge, pos_g, bias, out);
    } else {
        gemm_kernel<<<(N_NODES + 63) / 64, 256, 0, stream>>>(x, w, support);
        init_out_kernel<<<((N_NODES * OUT_F) + 255) / 256, 256, 0, stream>>>(bias, out);
        scatter_atomic_kernel<<<2048, 256, 0, stream>>>(support, erow, ecol, evals, out);
    }
}

// Round 11
// 154.191 us; speedup vs baseline: 1.0984x; 1.0102x over previous
//
#include <hip/hip_runtime.h>

#define N_NODES 100000
#define N_EDGES 1600000
#define IN_F 128
#define OUT_F 64

#define BROWS 64               // rows per bucket (ceil(100000/64) = 1563 buckets)
#define NBUCKET 1563
#define BK_PAD 136             // padded k-stride (shorts) for b_lds: breaks 16-way bank repeat

#define NCHUNK 512             // edge chunks; sort LDS = 31.3 KB -> 5 blocks/CU
#define EPC (N_EDGES / NCHUNK) // 3125 edges per chunk (exact)
#define NPOS (NBUCKET + 1)     // 1564: per-chunk prefix incl. sentinel
#define GEMM_BLKS ((N_NODES + 127) / 128)   // 782: gemm sub-blocks (128 rows each)

#define SLOTS 40               // per-row segment capacity (mean 16, P(>40) ~ 4e-8)
#define NSPILL 128             // spill list (insurance)

typedef __attribute__((ext_vector_type(8))) short bf16x8;
typedef __attribute__((ext_vector_type(4))) float f32x4;

__device__ __forceinline__ unsigned short f32_to_bf16(float f) {
    const unsigned int b = __float_as_uint(f);
    return (unsigned short)((b + 0x7FFFu + ((b >> 16) & 1u)) >> 16);   // RNE
}
__device__ __forceinline__ float bf16_to_f32(unsigned short u) {
    return __uint_as_float(((unsigned int)u) << 16);
}
// unpack low/high bf16 of a uint32 (1 VALU each)
__device__ __forceinline__ float bflo(unsigned int u) { return __uint_as_float(u << 16); }
__device__ __forceinline__ float bfhi(unsigned int u) { return __uint_as_float(u & 0xFFFF0000u); }

// ---------------- Kernel 1: FUSED  gemm (blocks >= NCHUNK) + chunk-sort (blocks < NCHUNK) ----
// Staged coalesced sedge writes (r5/r6 lesson: beats direct scatter) at full occupancy:
// sd 25 KB + pos 6.3 KB (64-row buckets -> 1564 counters) = 31.3 KB union -> 5 blocks/CU.
//
// gemm: 512 thr = 8 waves; wave = 16 rows x 64 cols via MFMA 16x16x32 bf16. W transposed
// in LDS as [n][k] bf16 (pad 136) -> b-frags are ds_read_b128. Frag layouts
// (m89/m91-verified): A: m=lane&15,k=quad*8+j. B: n=lane&15,k=quad*8+j.
// C/D: col=lane&15, row=quad*4+r.
__global__ __launch_bounds__(512) void gemm_sort_kernel(
    const float* __restrict__ x, const float* __restrict__ w,
    unsigned short* __restrict__ support,
    const int* __restrict__ erow, const int* __restrict__ ecol,
    const float* __restrict__ evals, int* __restrict__ pos_g,
    uint2* __restrict__ sedge) {
    __shared__ union {
        struct { uint2 sd[EPC]; int pos[NPOS]; int wofs[8]; } s;   // 31.3 KB (sort)
        unsigned short b[OUT_F * BK_PAD];                          // 17.4 KB (gemm)
    } u;

    const int t = threadIdx.x;

    if (blockIdx.x < NCHUNK) {
        // ================= sort branch =================
        int* pos = u.s.pos;
        uint2* sd = u.s.sd;
        const int c = blockIdx.x;
        const size_t e0 = (size_t)c * EPC;

        for (int i = t; i < NPOS; i += 512) pos[i] = 0;
        __syncthreads();

        // pass 1: histogram over 64-row buckets (erow re-read in pass 2 is L2-hot)
        #pragma unroll 1
        for (int j = t; j < EPC; j += 512)
            atomicAdd(&pos[erow[e0 + j] >> 6], 1);
        __syncthreads();

        // block-exclusive scan over 1563 buckets, 4 per thread (512*4 = 2048 >= 1564)
        int v[4]; int s = 0;
        #pragma unroll
        for (int j = 0; j < 4; ++j) {
            const int i = t * 4 + j;
            v[j] = (i < NBUCKET) ? pos[i] : 0;
            s += v[j];
        }
        const int lane = t & 63, wid = t >> 6;
        int incl = s;
        #pragma unroll
        for (int d = 1; d < 64; d <<= 1) { int tv = __shfl_up(incl, d); if (lane >= d) incl += tv; }
        if (lane == 63) u.s.wofs[wid] = incl;
        __syncthreads();
        int wbase = 0;
        #pragma unroll
        for (int wj = 0; wj < 8; ++wj) wbase += (wj < wid) ? u.s.wofs[wj] : 0;
        int ex = wbase + incl - s;
        #pragma unroll
        for (int j = 0; j < 4; ++j) {
            const int i = t * 4 + j;
            if (i < NBUCKET) { pos[i] = ex; ex += v[j]; }   // own indices only: no hazard
        }
        if (t == 0) pos[NBUCKET] = EPC;
        __syncthreads();

        // persist per-chunk prefix (coalesced); gather reads it directly (L2-resident)
        int* pg = pos_g + (size_t)c * NPOS;
        for (int i = t; i < NPOS; i += 512) pg[i] = pos[i];
        __syncthreads();   // persist reads must finish before cursors mutate

        // pass 2: rank + scatter to LDS staging
        #pragma unroll 1
        for (int j = t; j < EPC; j += 512) {
            const int row = erow[e0 + j];
            const int col = ecol[e0 + j];
            const float val = evals[e0 + j];
            const int r = atomicAdd(&pos[row >> 6], 1);
            uint2 ed;
            ed.x = (unsigned int)col | (((unsigned int)row & 63u) << 20);
            ed.y = __float_as_uint(val);
            sd[r] = ed;
        }
        __syncthreads();

        // write sorted chunk, fully coalesced
        uint2* sg = sedge + e0;
        for (int i = t; i < EPC; i += 512) sg[i] = sd[i];
        return;
    }

    // ================= gemm branch =================
    const int bb = blockIdx.x - NCHUNK;
    // stage W transposed: w[k][n] (fp32, coalesced float4) -> b[n*BK_PAD + k] (bf16)
    #pragma unroll
    for (int i = 0; i < 4; ++i) {
        const int f = t + 512 * i;            // float4 index; k = f>>4, n4 = (f&15)*4
        const int k = f >> 4, n4 = (f & 15) * 4;
        const float4 wv = ((const float4*)w)[f];
        u.b[(n4 + 0) * BK_PAD + k] = f32_to_bf16(wv.x);
        u.b[(n4 + 1) * BK_PAD + k] = f32_to_bf16(wv.y);
        u.b[(n4 + 2) * BK_PAD + k] = f32_to_bf16(wv.z);
        u.b[(n4 + 3) * BK_PAD + k] = f32_to_bf16(wv.w);
    }
    __syncthreads();

    const int lane = t & 63, wid = t >> 6;
    const int m16 = lane & 15, quad = lane >> 4;
    const int row0 = bb * 128 + wid * 16;
    const int arow = min(row0 + m16, N_NODES - 1);
    const float* xr = x + (size_t)arow * IN_F;

    f32x4 acc[4];
    #pragma unroll
    for (int nt = 0; nt < 4; ++nt) acc[nt] = (f32x4){0.f, 0.f, 0.f, 0.f};

    #pragma unroll
    for (int kt = 0; kt < 4; ++kt) {
        const int kb = kt * 32 + quad * 8;
        const float4 a0 = *(const float4*)(xr + kb);
        const float4 a1 = *(const float4*)(xr + kb + 4);
        bf16x8 af;
        af[0] = (short)f32_to_bf16(a0.x); af[1] = (short)f32_to_bf16(a0.y);
        af[2] = (short)f32_to_bf16(a0.z); af[3] = (short)f32_to_bf16(a0.w);
        af[4] = (short)f32_to_bf16(a1.x); af[5] = (short)f32_to_bf16(a1.y);
        af[6] = (short)f32_to_bf16(a1.z); af[7] = (short)f32_to_bf16(a1.w);
        #pragma unroll
        for (int nt = 0; nt < 4; ++nt) {
            const bf16x8 bf = *(const bf16x8*)&u.b[(nt * 16 + m16) * BK_PAD + kb];
            acc[nt] = __builtin_amdgcn_mfma_f32_16x16x32_bf16(af, bf, acc[nt], 0, 0, 0);
        }
    }

    #pragma unroll
    for (int nt = 0; nt < 4; ++nt) {
        #pragma unroll
        for (int r = 0; r < 4; ++r) {
            const int row = row0 + quad * 4 + r;
            if (row < N_NODES)
                support[(size_t)row * OUT_F + nt * 16 + m16] = f32_to_bf16(acc[nt][r]);
        }
    }
}

// predicated quad tail (0..3 live edges of the 4-group)
#define QUADT(A0, A1, A2, A3, J, E) do { \
    const int jj = (J) + eg; const bool act = jj < (E); \
    const uint2 q = sdata[act ? jj : (J)]; \
    const float w = act ? __uint_as_float(q.y) : 0.f; \
    const uint2 h = *(const uint2*)(support + (size_t)(q.x & 0xFFFFFu) * OUT_F + c4 * 4); \
    A0 += w * bflo(h.x); A1 += w * bfhi(h.x); A2 += w * bflo(h.y); A3 += w * bfhi(h.y); \
} while (0)

// place one edge into its row segment
#define PLACE(ED) do { \
    const int r_ = ((ED).x >> 20) & 63; \
    const int sl_ = atomicAdd(&rcnt[r_], 1); \
    if (sl_ < SLOTS) sdata[r_ * SLOTS + sl_] = (ED); \
    else { const int q_ = atomicAdd(&nspill, 1); if (q_ < NSPILL) spill[q_] = (ED); } \
} while (0)

// ---------------- Kernel 2: gather = one-pass segment placement + accumulation ---------------
// r10 structure with the back-end's dependent tail removed: per row, ONE predicated
// 24-edge batch (6 LDS edge reads -> 6 independent support gathers -> FMAs, as
// separate unrolled phases so all 6 global loads issue with no intervening
// dependence). r10's QUAD16+QUAD8/QUADT serialized a SECOND latency round-trip for
// the ~50% of rows with cnt>16 (Poisson(16)); the batch covers cnt<=24 (~98%) in one
// round-trip. Predication: fallback index = row slot 0 (initialized when cnt>0),
// weight 0; cnt==0 rows skip via wave-uniform branch. cnt 25..40 tail ~2%, QUADT.
// __launch_bounds__(512,8) pins VGPR<=64 so 4 blocks/CU (32 waves) is preserved.
// Front-end unchanged (proven r10): 4-deep batched run head, LDS segment placement.
// Bijective XCD swizzle (1563 = 8*195+3) for sedge/pos_g L2 locality.
__global__ __launch_bounds__(512, 8) void gather_kernel(
    const unsigned short* __restrict__ support, const uint2* __restrict__ sedge,
    const int* __restrict__ pos_g, const float* __restrict__ bias,
    float* __restrict__ out) {
    __shared__ uint2 sdata[BROWS * SLOTS];   // 20.5 KB row segments
    __shared__ uint2 spill[NSPILL];          // 1 KB (statistically never used)
    __shared__ int rcnt[BROWS];
    __shared__ int nspill;

    const int t = threadIdx.x;
    // nwg = 1563 = 8*195 + 3: xcd<3 owns 196 buckets, else 195 (bijective, m204)
    const int orig = blockIdx.x;
    const int xcd = orig & 7, loc = orig >> 3;
    const int k = (xcd < 3 ? xcd * 196 : 3 * 196 + (xcd - 3) * 195) + loc;
    const int lane = t & 63, wid = t >> 6;

    if (t < BROWS) rcnt[t] = 0;
    if (t == 0) nspill = 0;
    __syncthreads();

    // one-pass placement: thread t owns chunk t (pos_g[t][k], pos_g[t][k+1] share a
    // cache line; pos_g 3.2 MB -> L2-resident). 4-deep batched load head.
    {
        const int s = pos_g[(size_t)t * NPOS + k];
        const int e = pos_g[(size_t)t * NPOS + k + 1];
        const int L = e - s;
        const uint2* run = sedge + (size_t)t * EPC;
        uint2 b0, b1, b2, b3;
        if (L > 0) b0 = run[s];
        if (L > 1) b1 = run[s + 1];
        if (L > 2) b2 = run[s + 2];
        if (L > 3) b3 = run[s + 3];
        if (L > 0) PLACE(b0);
        if (L > 1) PLACE(b1);
        if (L > 2) PLACE(b2);
        if (L > 3) PLACE(b3);
        #pragma unroll 1
        for (int j = s + 4; j < e; j += 2) {     // rare tail (P ~ 5%), 2-deep
            uint2 c0 = run[j]; uint2 c1;
            const bool h2 = (j + 1) < e;
            if (h2) c1 = run[j + 1];
            PLACE(c0);
            if (h2) PLACE(c1);
        }
    }
    __syncthreads();

    const int eg = lane >> 4;          // edge-group 0..3
    const int c4 = lane & 15;          // col-quad: cols 4*c4 .. 4*c4+3
    const float4 bb = ((const float4*)bias)[c4];

    for (int r8i = 0; r8i < 8; ++r8i) {
        const int r = wid * 8 + r8i;
        const int cnt = min(rcnt[r], SLOTS);
        const int s0 = r * SLOTS;
        float a0 = 0.f, a1 = 0.f, a2 = 0.f, a3 = 0.f;
        if (cnt > 0) {                 // wave-uniform branch (all lanes share r)
            // phase A: 6 predicated LDS edge reads (24 edges, covers ~98% of rows)
            uint2 q0, q1, q2, q3, q4, q5;
            q0 = sdata[(0 * 4 + eg) < cnt ? s0 + 0 * 4 + eg : s0];
            q1 = sdata[(1 * 4 + eg) < cnt ? s0 + 1 * 4 + eg : s0];
            q2 = sdata[(2 * 4 + eg) < cnt ? s0 + 2 * 4 + eg : s0];
            q3 = sdata[(3 * 4 + eg) < cnt ? s0 + 3 * 4 + eg : s0];
            q4 = sdata[(4 * 4 + eg) < cnt ? s0 + 4 * 4 + eg : s0];
            q5 = sdata[(5 * 4 + eg) < cnt ? s0 + 5 * 4 + eg : s0];
            // phase B: 6 independent support gathers — all in flight together
            const uint2 h0 = *(const uint2*)(support + (size_t)(q0.x & 0xFFFFFu) * OUT_F + c4 * 4);
            const uint2 h1 = *(const uint2*)(support + (size_t)(q1.x & 0xFFFFFu) * OUT_F + c4 * 4);
            const uint2 h2 = *(const uint2*)(support + (size_t)(q2.x & 0xFFFFFu) * OUT_F + c4 * 4);
            const uint2 h3 = *(const uint2*)(support + (size_t)(q3.x & 0xFFFFFu) * OUT_F + c4 * 4);
            const uint2 h4 = *(const uint2*)(support + (size_t)(q4.x & 0xFFFFFu) * OUT_F + c4 * 4);
            const uint2 h5 = *(const uint2*)(support + (size_t)(q5.x & 0xFFFFFu) * OUT_F + c4 * 4);
            // phase C: predicated weights + FMAs
            const float w0 = (0 * 4 + eg) < cnt ? __uint_as_float(q0.y) : 0.f;
            const float w1 = (1 * 4 + eg) < cnt ? __uint_as_float(q1.y) : 0.f;
            const float w2 = (2 * 4 + eg) < cnt ? __uint_as_float(q2.y) : 0.f;
            const float w3 = (3 * 4 + eg) < cnt ? __uint_as_float(q3.y) : 0.f;
            const float w4 = (4 * 4 + eg) < cnt ? __uint_as_float(q4.y) : 0.f;
            const float w5 = (5 * 4 + eg) < cnt ? __uint_as_float(q5.y) : 0.f;
            a0 += w0 * bflo(h0.x); a1 += w0 * bfhi(h0.x); a2 += w0 * bflo(h0.y); a3 += w0 * bfhi(h0.y);
            a0 += w1 * bflo(h1.x); a1 += w1 * bfhi(h1.x); a2 += w1 * bflo(h1.y); a3 += w1 * bfhi(h1.y);
            a0 += w2 * bflo(h2.x); a1 += w2 * bfhi(h2.x); a2 += w2 * bflo(h2.y); a3 += w2 * bfhi(h2.y);
            a0 += w3 * bflo(h3.x); a1 += w3 * bfhi(h3.x); a2 += w3 * bflo(h3.y); a3 += w3 * bfhi(h3.y);
            a0 += w4 * bflo(h4.x); a1 += w4 * bfhi(h4.x); a2 += w4 * bflo(h4.y); a3 += w4 * bfhi(h4.y);
            a0 += w5 * bflo(h5.x); a1 += w5 * bfhi(h5.x); a2 += w5 * bflo(h5.y); a3 += w5 * bfhi(h5.y);
            // rare tail: cnt in (24, 40] (~2% of rows)
            for (int j = s0 + 24; j < s0 + cnt; j += 4)
                QUADT(a0, a1, a2, a3, j, s0 + cnt);
        }
        a0 += __shfl_xor(a0, 16); a0 += __shfl_xor(a0, 32);
        a1 += __shfl_xor(a1, 16); a1 += __shfl_xor(a1, 32);
        a2 += __shfl_xor(a2, 16); a2 += __shfl_xor(a2, 32);
        a3 += __shfl_xor(a3, 16); a3 += __shfl_xor(a3, 32);
        const int node = k * BROWS + r;
        if (eg == 0 && node < N_NODES) {         // last bucket has 32 valid rows
            float4 o;
            o.x = a0 + bb.x; o.y = a1 + bb.y; o.z = a2 + bb.z; o.w = a3 + bb.w;
            *(float4*)(out + (size_t)node * OUT_F + c4 * 4) = o;
        }
    }

    if (nspill > 0) {   // insurance: rows with >SLOTS edges (P ~ 4e-8 per row)
        __syncthreads();                       // out stores drained (vmcnt@barrier)
        const int ns = min(nspill, NSPILL);
        for (int i = wid; i < ns; i += 8) {    // wave per edge, lane = column
            const uint2 ed = spill[i];
            const float g = bf16_to_f32(support[(size_t)(ed.x & 0xFFFFFu) * OUT_F + lane]);
            atomicAdd(&out[(size_t)(k * BROWS + ((ed.x >> 20) & 63)) * OUT_F + lane],
                      g * __uint_as_float(ed.y));
        }
    }
}

// ---------------- Fallback (ws too small): gemm-only + bias-init + atomic scatter ----------
__global__ __launch_bounds__(256) void gemm_kernel(
    const float* __restrict__ x, const float* __restrict__ w,
    unsigned short* __restrict__ support) {
    __shared__ unsigned short b_lds[OUT_F * BK_PAD];
    const int t = threadIdx.x;
    #pragma unroll
    for (int i = 0; i < 8; ++i) {
        const int f = t + 256 * i;
        const int k = f >> 4, n4 = (f & 15) * 4;
        const float4 wv = ((const float4*)w)[f];
        b_lds[(n4 + 0) * BK_PAD + k] = f32_to_bf16(wv.x);
        b_lds[(n4 + 1) * BK_PAD + k] = f32_to_bf16(wv.y);
        b_lds[(n4 + 2) * BK_PAD + k] = f32_to_bf16(wv.z);
        b_lds[(n4 + 3) * BK_PAD + k] = f32_to_bf16(wv.w);
    }
    __syncthreads();
    const int lane = t & 63, wid = t >> 6;
    const int m16 = lane & 15, quad = lane >> 4;
    const int row0 = blockIdx.x * 64 + wid * 16;
    const int arow = min(row0 + m16, N_NODES - 1);
    const float* xr = x + (size_t)arow * IN_F;
    f32x4 acc[4];
    #pragma unroll
    for (int nt = 0; nt < 4; ++nt) acc[nt] = (f32x4){0.f, 0.f, 0.f, 0.f};
    #pragma unroll
    for (int kt = 0; kt < 4; ++kt) {
        const int kb = kt * 32 + quad * 8;
        const float4 a0 = *(const float4*)(xr + kb);
        const float4 a1 = *(const float4*)(xr + kb + 4);
        bf16x8 af;
        af[0] = (short)f32_to_bf16(a0.x); af[1] = (short)f32_to_bf16(a0.y);
        af[2] = (short)f32_to_bf16(a0.z); af[3] = (short)f32_to_bf16(a0.w);
        af[4] = (short)f32_to_bf16(a1.x); af[5] = (short)f32_to_bf16(a1.y);
        af[6] = (short)f32_to_bf16(a1.z); af[7] = (short)f32_to_bf16(a1.w);
        #pragma unroll
        for (int nt = 0; nt < 4; ++nt) {
            const bf16x8 bf = *(const bf16x8*)&b_lds[(nt * 16 + m16) * BK_PAD + kb];
            acc[nt] = __builtin_amdgcn_mfma_f32_16x16x32_bf16(af, bf, acc[nt], 0, 0, 0);
        }
    }
    #pragma unroll
    for (int nt = 0; nt < 4; ++nt) {
        #pragma unroll
        for (int r = 0; r < 4; ++r) {
            const int row = row0 + quad * 4 + r;
            if (row < N_NODES)
                support[(size_t)row * OUT_F + nt * 16 + m16] = f32_to_bf16(acc[nt][r]);
        }
    }
}
__global__ __launch_bounds__(256) void init_out_kernel(const float* __restrict__ bias,
                                                       float* __restrict__ out) {
    const size_t i = (size_t)blockIdx.x * 256 + threadIdx.x;
    if (i < (size_t)N_NODES * OUT_F) out[i] = bias[i & 63];
}
__global__ __launch_bounds__(256) void scatter_atomic_kernel(
    const unsigned short* __restrict__ support, const int* __restrict__ erow,
    const int* __restrict__ ecol, const float* __restrict__ evals,
    float* __restrict__ out) {
    const int wid = (blockIdx.x * 256 + threadIdx.x) >> 6;
    const int nw = gridDim.x * 4;
    const int lane = threadIdx.x & 63;
    const int n_iters = N_EDGES / 8;
    for (int it0 = wid; it0 < n_iters; it0 += nw) {
        const int e0 = __builtin_amdgcn_readfirstlane(it0) * 8;
        int src[8], dst[8]; float val[8];
        #pragma unroll
        for (int u = 0; u < 8; ++u) { src[u] = ecol[e0 + u]; dst[u] = erow[e0 + u]; val[u] = evals[e0 + u]; }
        float g[8];
        #pragma unroll
        for (int u = 0; u < 8; ++u) g[u] = bf16_to_f32(support[(size_t)src[u] * OUT_F + lane]);
        #pragma unroll
        for (int u = 0; u < 8; ++u) atomicAdd(&out[(size_t)dst[u] * OUT_F + lane], g[u] * val[u]);
    }
}

extern "C" void kernel_launch(void* const* d_in, const int* in_sizes, int n_in,
                              void* d_out, int out_size, void* d_ws, size_t ws_size,
                              hipStream_t stream) {
    const float* x     = (const float*)d_in[0];
    const float* w     = (const float*)d_in[1];
    const float* bias  = (const float*)d_in[2];
    const int* erow    = (const int*)d_in[3];
    const int* ecol    = (const int*)d_in[4];
    const float* evals = (const float*)d_in[5];
    float* out = (float*)d_out;

    char* p = (char*)d_ws;
    unsigned short* support = (unsigned short*)p;  size_t o = (size_t)N_NODES * OUT_F * 2;   // 12.8 MB
    int* pos_g = (int*)(p + o);                    o += (size_t)NCHUNK * NPOS * 4;            // 3.2 MB
    uint2* sedge = (uint2*)(p + o);                o += (size_t)N_EDGES * 8;                  // 12.8 MB

    if (ws_size >= o) {
        gemm_sort_kernel<<<NCHUNK + GEMM_BLKS, 512, 0, stream>>>(
            x, w, support, erow, ecol, evals, pos_g, sedge);
        gather_kernel<<<NBUCKET, 512, 0, stream>>>(support, sedge, pos_g, bias, out);
    } else {
        gemm_kernel<<<(N_NODES + 63) / 64, 256, 0, stream>>>(x, w, support);
        init_out_kernel<<<((N_NODES * OUT_F) + 255) / 256, 256, 0, stream>>>(bias, out);
        scatter_atomic_kernel<<<2048, 256, 0, stream>>>(support, erow, ecol, evals, out);
    }
}